// Round 3
// baseline (1027.210 us; speedup 1.0000x reference)
//
#include <hip/hip_runtime.h>
#include <math.h>

#define N_NODES 10000
#define N_EDGES 160000
#define HIDDEN 128
#define NUM_RBF 32
#define LATENT 64
#define N_GRAPHS 128
#define CUTOFF 5.0f
#define EPS 1e-8f

__device__ __forceinline__ float silu(float v) { return v / (1.0f + expf(-v)); }

__global__ void zero_f_kernel(float* __restrict__ p, int n) {
    int i = blockIdx.x * blockDim.x + threadIdx.x;
    if (i < n) p[i] = 0.0f;
}
__global__ void zero_i_kernel(int* __restrict__ p, int n) {
    int i = blockIdx.x * blockDim.x + threadIdx.x;
    if (i < n) p[i] = 0;
}

__global__ void hist_kernel(const int* __restrict__ dst, int* __restrict__ deg) {
    int e = blockIdx.x * blockDim.x + threadIdx.x;
    if (e < N_EDGES) atomicAdd(&deg[dst[e]], 1);
}

// single block, 1024 threads: exclusive prefix over deg[10000] -> cursor
__global__ void prefix_kernel(const int* __restrict__ deg, int* __restrict__ cursor) {
    __shared__ int part[1024];
    const int ITEMS = 10;
    int t = threadIdx.x;
    int base = t * ITEMS;
    int local[ITEMS];
    int s = 0;
#pragma unroll
    for (int j = 0; j < ITEMS; j++) {
        int idx = base + j;
        int v = (idx < N_NODES) ? deg[idx] : 0;
        local[j] = s;
        s += v;
    }
    part[t] = s;
    __syncthreads();
    for (int off = 1; off < 1024; off <<= 1) {
        int v = (t >= off) ? part[t - off] : 0;
        __syncthreads();
        part[t] += v;
        __syncthreads();
    }
    int base_sum = (t > 0) ? part[t - 1] : 0;
#pragma unroll
    for (int j = 0; j < ITEMS; j++) {
        int idx = base + j;
        if (idx < N_NODES) cursor[idx] = base_sum + local[j];
    }
}

// eperm[p]=e, sperm[p]=src[e], dperm[p]=dst[e], rows sorted by dst
__global__ void scatter_kernel(const int* __restrict__ src, const int* __restrict__ dst,
                               int* __restrict__ cursor, int* __restrict__ eperm,
                               int* __restrict__ sperm, int* __restrict__ dperm) {
    int e = blockIdx.x * blockDim.x + threadIdx.x;
    if (e < N_EDGES) {
        int d = dst[e];
        int p = atomicAdd(&cursor[d], 1);
        eperm[p] = e;
        sperm[p] = src[e];
        dperm[p] = d;
    }
}

// geometry written in PERMUTED row order: rbf[i], dirn[i] for i-th dst-sorted edge
__global__ void geom_kernel(const float* __restrict__ pos, const int* __restrict__ ei,
                            const int* __restrict__ eperm, float* __restrict__ rbf,
                            float* __restrict__ dirn) {
    int i = blockIdx.x * blockDim.x + threadIdx.x;
    if (i >= N_EDGES) return;
    int e = eperm[i];
    int s = ei[e];
    int t = ei[N_EDGES + e];
    float dx = pos[t * 3 + 0] - pos[s * 3 + 0];
    float dy = pos[t * 3 + 1] - pos[s * 3 + 1];
    float dz = pos[t * 3 + 2] - pos[s * 3 + 2];
    float r = sqrtf(dx * dx + dy * dy + dz * dz + EPS);
    float inv = 1.0f / r;
    dirn[i * 3 + 0] = dx * inv;
    dirn[i * 3 + 1] = dy * inv;
    dirn[i * 3 + 2] = dz * inv;

    float e5 = expf(-CUTOFF);
    float span = 1.0f - e5;
    float b = (2.0f / NUM_RBF) * span;
    float beta = 1.0f / (b * b);
    float cut = (r < CUTOFF) ? 0.5f * (cosf((float)M_PI * r / CUTOFF) + 1.0f) : 0.0f;
    float er = expf(-r);
#pragma unroll
    for (int k = 0; k < NUM_RBF; k++) {
        float mean = e5 + span * ((float)k / (NUM_RBF - 1));
        float d = er - mean;
        rbf[i * NUM_RBF + k] = cut * expf(-beta * d * d);
    }
}

__global__ void init_x_kernel(const int* __restrict__ z, const float* __restrict__ embed,
                              float* __restrict__ x) {
    int i = blockIdx.x * blockDim.x + threadIdx.x;
    if (i < N_NODES * HIDDEN) {
        int n = i >> 7;
        int h = i & 127;
        x[i] = embed[z[n] * HIDDEN + h];
    }
}

// ---------------- generic tiled GEMM: C = epi(A[MxK] @ W[Kx128]) ----------------
// EPI bits: 1=bias, 2=add Cin, 4=silu
template <int K, int EPI>
__global__ __launch_bounds__(256) void gemm_nn(const float* __restrict__ A,
                                               const float* __restrict__ W,
                                               const float* __restrict__ bias,
                                               const float* __restrict__ Cin,
                                               float* __restrict__ C, int M) {
    constexpr int STR = K + 4;
    __shared__ float As[64 * STR];
    int tid = threadIdx.x;
    int rg = tid >> 5;
    int cg = tid & 31;
    int row0 = blockIdx.x * 64;

    for (int idx = tid; idx < 64 * (K / 4); idx += 256) {
        int r = idx / (K / 4);
        int k4 = idx % (K / 4);
        float4 v = make_float4(0.f, 0.f, 0.f, 0.f);
        if (row0 + r < M) v = *(const float4*)(A + (size_t)(row0 + r) * K + k4 * 4);
        *(float4*)(As + r * STR + k4 * 4) = v;
    }
    __syncthreads();

    float acc[8][4];
#pragma unroll
    for (int i = 0; i < 8; i++)
#pragma unroll
        for (int j = 0; j < 4; j++) acc[i][j] = 0.f;

    const float* Wp = W + cg * 4;
#pragma unroll 4
    for (int k4 = 0; k4 < K / 4; k4++) {
        float4 w0 = *(const float4*)(Wp + (k4 * 4 + 0) * 128);
        float4 w1 = *(const float4*)(Wp + (k4 * 4 + 1) * 128);
        float4 w2 = *(const float4*)(Wp + (k4 * 4 + 2) * 128);
        float4 w3 = *(const float4*)(Wp + (k4 * 4 + 3) * 128);
#pragma unroll
        for (int i = 0; i < 8; i++) {
            float4 av = *(const float4*)(As + (rg * 8 + i) * STR + k4 * 4);
            acc[i][0] += av.x * w0.x + av.y * w1.x + av.z * w2.x + av.w * w3.x;
            acc[i][1] += av.x * w0.y + av.y * w1.y + av.z * w2.y + av.w * w3.y;
            acc[i][2] += av.x * w0.z + av.y * w1.z + av.z * w2.z + av.w * w3.z;
            acc[i][3] += av.x * w0.w + av.y * w1.w + av.z * w2.w + av.w * w3.w;
        }
    }

    float4 bv = make_float4(0.f, 0.f, 0.f, 0.f);
    if (EPI & 1) bv = *(const float4*)(bias + cg * 4);
#pragma unroll
    for (int i = 0; i < 8; i++) {
        int r = row0 + rg * 8 + i;
        if (r < M) {
            float4 o;
            o.x = acc[i][0] + bv.x;
            o.y = acc[i][1] + bv.y;
            o.z = acc[i][2] + bv.z;
            o.w = acc[i][3] + bv.w;
            if (EPI & 2) {
                float4 ci = *(const float4*)(Cin + (size_t)r * 128 + cg * 4);
                o.x += ci.x; o.y += ci.y; o.z += ci.z; o.w += ci.w;
            }
            if (EPI & 4) {
                o.x = silu(o.x); o.y = silu(o.y); o.z = silu(o.z); o.w = silu(o.w);
            }
            *(float4*)(C + (size_t)r * 128 + cg * 4) = o;
        }
    }
}

// ------------- fused edge kernel: filt -> t -> phi -> segmented dst-reduction -> atomics -------------
// Rows are dst-sorted edges. No filt/phi round-trip to HBM.
__global__ __launch_bounds__(256) void edge_fused(
    const float* __restrict__ rbf, const float* __restrict__ Wrbf, const float* __restrict__ x,
    const int* __restrict__ sperm, const int* __restrict__ dperm, const float* __restrict__ W1,
    const float* __restrict__ dirn, const float* __restrict__ vmix, float* __restrict__ dxb,
    float* __restrict__ vec) {
    __shared__ float Smem[64 * 132];  // aliased: rbf tile (stride 36) then t tile (stride 132)
    __shared__ int s_src[64];
    __shared__ int s_dst[64];
    __shared__ float s_dir[64 * 3];
    int tid = threadIdx.x;
    int rg = tid >> 5;
    int cg = tid & 31;
    int row0 = blockIdx.x * 64;

    for (int idx = tid; idx < 64 * 8; idx += 256) {
        int r = idx >> 3;
        int k4 = idx & 7;
        *(float4*)(Smem + r * 36 + k4 * 4) =
            *(const float4*)(rbf + (size_t)(row0 + r) * 32 + k4 * 4);
    }
    if (tid < 64) {
        s_src[tid] = sperm[row0 + tid];
        s_dst[tid] = dperm[row0 + tid];
    }
    if (tid < 192) s_dir[tid] = dirn[(size_t)row0 * 3 + tid];
    __syncthreads();

    // filt = rbf @ Wrbf  (K=32)
    float fa[8][4];
#pragma unroll
    for (int i = 0; i < 8; i++)
#pragma unroll
        for (int j = 0; j < 4; j++) fa[i][j] = 0.f;
    {
        const float* Wp = Wrbf + cg * 4;
#pragma unroll
        for (int k4 = 0; k4 < 8; k4++) {
            float4 w0 = *(const float4*)(Wp + (k4 * 4 + 0) * 128);
            float4 w1 = *(const float4*)(Wp + (k4 * 4 + 1) * 128);
            float4 w2 = *(const float4*)(Wp + (k4 * 4 + 2) * 128);
            float4 w3 = *(const float4*)(Wp + (k4 * 4 + 3) * 128);
#pragma unroll
            for (int i = 0; i < 8; i++) {
                float4 av = *(const float4*)(Smem + (rg * 8 + i) * 36 + k4 * 4);
                fa[i][0] += av.x * w0.x + av.y * w1.x + av.z * w2.x + av.w * w3.x;
                fa[i][1] += av.x * w0.y + av.y * w1.y + av.z * w2.y + av.w * w3.y;
                fa[i][2] += av.x * w0.z + av.y * w1.z + av.z * w2.z + av.w * w3.z;
                fa[i][3] += av.x * w0.w + av.y * w1.w + av.z * w2.w + av.w * w3.w;
            }
        }
    }
    __syncthreads();  // done reading rbf tile; Smem about to be overwritten

    // t = filt * x[src] -> LDS (stride 132)
#pragma unroll
    for (int i = 0; i < 8; i++) {
        int r = rg * 8 + i;
        float4 xv = *(const float4*)(x + (size_t)s_src[r] * 128 + cg * 4);
        float4 t;
        t.x = fa[i][0] * xv.x;
        t.y = fa[i][1] * xv.y;
        t.z = fa[i][2] * xv.z;
        t.w = fa[i][3] * xv.w;
        *(float4*)(Smem + r * 132 + cg * 4) = t;
    }
    __syncthreads();

    // phi = silu(t @ W1)  (K=128)
    float pa[8][4];
#pragma unroll
    for (int i = 0; i < 8; i++)
#pragma unroll
        for (int j = 0; j < 4; j++) pa[i][j] = 0.f;
    {
        const float* Wp = W1 + cg * 4;
#pragma unroll 4
        for (int k4 = 0; k4 < 32; k4++) {
            float4 w0 = *(const float4*)(Wp + (k4 * 4 + 0) * 128);
            float4 w1 = *(const float4*)(Wp + (k4 * 4 + 1) * 128);
            float4 w2 = *(const float4*)(Wp + (k4 * 4 + 2) * 128);
            float4 w3 = *(const float4*)(Wp + (k4 * 4 + 3) * 128);
#pragma unroll
            for (int i = 0; i < 8; i++) {
                float4 av = *(const float4*)(Smem + (rg * 8 + i) * 132 + k4 * 4);
                pa[i][0] += av.x * w0.x + av.y * w1.x + av.z * w2.x + av.w * w3.x;
                pa[i][1] += av.x * w0.y + av.y * w1.y + av.z * w2.y + av.w * w3.y;
                pa[i][2] += av.x * w0.z + av.y * w1.z + av.z * w2.z + av.w * w3.z;
                pa[i][3] += av.x * w0.w + av.y * w1.w + av.z * w2.w + av.w * w3.w;
            }
        }
    }

    // segmented reduction over dst runs within this thread's 8 rows
    float rdx[4] = {0.f, 0.f, 0.f, 0.f};
    float rv[3][4];
#pragma unroll
    for (int c = 0; c < 3; c++)
#pragma unroll
        for (int j = 0; j < 4; j++) rv[c][j] = 0.f;
    int cur = -1;
    int colbase = cg * 4;
#pragma unroll
    for (int i = 0; i < 8; i++) {
        int r = rg * 8 + i;
        int d = s_dst[r];
        if (d != cur) {
            if (cur >= 0) {
#pragma unroll
                for (int j = 0; j < 4; j++)
                    atomicAdd(&dxb[(size_t)cur * 128 + colbase + j], rdx[j]);
#pragma unroll
                for (int c = 0; c < 3; c++)
#pragma unroll
                    for (int j = 0; j < 4; j++)
                        atomicAdd(&vec[((size_t)cur * 3 + c) * 128 + colbase + j], rv[c][j]);
            }
            cur = d;
#pragma unroll
            for (int j = 0; j < 4; j++) rdx[j] = 0.f;
#pragma unroll
            for (int c = 0; c < 3; c++)
#pragma unroll
                for (int j = 0; j < 4; j++) rv[c][j] = 0.f;
        }
        float ph[4];
        ph[0] = silu(pa[i][0]);
        ph[1] = silu(pa[i][1]);
        ph[2] = silu(pa[i][2]);
        ph[3] = silu(pa[i][3]);
        const float* vm = vmix + (size_t)s_src[r] * 384 + colbase;
        float d0 = s_dir[r * 3 + 0];
        float d1 = s_dir[r * 3 + 1];
        float d2 = s_dir[r * 3 + 2];
        float4 v0 = *(const float4*)(vm);
        float4 v1 = *(const float4*)(vm + 128);
        float4 v2 = *(const float4*)(vm + 256);
#pragma unroll
        for (int j = 0; j < 4; j++) rdx[j] += ph[j];
        rv[0][0] += v0.x * fa[i][0] + ph[0] * d0;
        rv[0][1] += v0.y * fa[i][1] + ph[1] * d0;
        rv[0][2] += v0.z * fa[i][2] + ph[2] * d0;
        rv[0][3] += v0.w * fa[i][3] + ph[3] * d0;
        rv[1][0] += v1.x * fa[i][0] + ph[0] * d1;
        rv[1][1] += v1.y * fa[i][1] + ph[1] * d1;
        rv[1][2] += v1.z * fa[i][2] + ph[2] * d1;
        rv[1][3] += v1.w * fa[i][3] + ph[3] * d1;
        rv[2][0] += v2.x * fa[i][0] + ph[0] * d2;
        rv[2][1] += v2.y * fa[i][1] + ph[1] * d2;
        rv[2][2] += v2.z * fa[i][2] + ph[2] * d2;
        rv[2][3] += v2.w * fa[i][3] + ph[3] * d2;
    }
#pragma unroll
    for (int j = 0; j < 4; j++) atomicAdd(&dxb[(size_t)cur * 128 + colbase + j], rdx[j]);
#pragma unroll
    for (int c = 0; c < 3; c++)
#pragma unroll
        for (int j = 0; j < 4; j++)
            atomicAdd(&vec[((size_t)cur * 3 + c) * 128 + colbase + j], rv[c][j]);
}

// vnorm[n][h] = sqrt(sum_c v2[n][c][h]^2 + EPS)
__global__ void vnorm_kernel(const float* __restrict__ v2, float* __restrict__ vnorm) {
    int i = blockIdx.x * blockDim.x + threadIdx.x;
    if (i >= N_NODES * HIDDEN) return;
    int n = i >> 7;
    int h = i & 127;
    float a = v2[(size_t)(n * 3 + 0) * 128 + h];
    float b = v2[(size_t)(n * 3 + 1) * 128 + h];
    float c = v2[(size_t)(n * 3 + 2) * 128 + h];
    vnorm[i] = sqrtf(a * a + b * b + c * c + EPS);
}

__global__ void out_pool_kernel(const float* __restrict__ a, const float* __restrict__ W_b,
                                const float* __restrict__ b_b, const int* __restrict__ batch,
                                float* __restrict__ pooled) {
    __shared__ float sa[HIDDEN];
    int n = blockIdx.x;
    int h = threadIdx.x;
    sa[h] = a[(size_t)n * 128 + h];
    __syncthreads();
    if (h < LATENT + 1) {
        float o = b_b[h];
        for (int j = 0; j < HIDDEN; j++) o += sa[j] * W_b[j * (LATENT + 1) + h];
        atomicAdd(&pooled[batch[n] * (LATENT + 1) + h], o);
    }
}

__global__ void finalize_kernel(const float* __restrict__ pooled, float* __restrict__ out) {
    int i = blockIdx.x * blockDim.x + threadIdx.x;
    if (i >= N_GRAPHS * (LATENT + 1)) return;
    int g = i / (LATENT + 1);
    int k = i % (LATENT + 1);
    float v = pooled[i];
    if (k < LATENT) {
        out[g * LATENT + k] = v;
    } else {
        v = fminf(fmaxf(v, -10.0f), 2.0f);
        out[N_GRAPHS * LATENT + g] = v;
    }
}

extern "C" void kernel_launch(void* const* d_in, const int* in_sizes, int n_in,
                              void* d_out, int out_size, void* d_ws, size_t ws_size,
                              hipStream_t stream) {
    const int* z = (const int*)d_in[0];
    const float* pos = (const float*)d_in[1];
    const int* batch = (const int*)d_in[2];
    const int* ei = (const int*)d_in[3];
    const float* embed = (const float*)d_in[4];
    const float* W_rbf = (const float*)d_in[5];
    const float* W1 = (const float*)d_in[6];
    const float* Wo = (const float*)d_in[7];
    const float* Wv = (const float*)d_in[8];
    const float* Wvec2 = (const float*)d_in[10];
    const float* W_a = (const float*)d_in[11];
    const float* b_a = (const float*)d_in[12];
    const float* W_b = (const float*)d_in[13];
    const float* b_b = (const float*)d_in[14];
    float* out = (float*)d_out;

    const int* srcs = ei;
    const int* dsts = ei + N_EDGES;

    float* ws = (float*)d_ws;
    float* rbf = ws;                               // E*32 (permuted order)
    float* dirn = rbf + (size_t)N_EDGES * 32;      // E*3  (permuted order)
    float* x = dirn + (size_t)N_EDGES * 3;         // N*128
    float* vec = x + (size_t)N_NODES * 128;        // N*384
    float* vmix = vec + (size_t)N_NODES * 384;     // N*384 (later reused as v2)
    float* dxb = vmix + (size_t)N_NODES * 384;     // N*128 (later reused as vnorm)
    float* tmpa = dxb + (size_t)N_NODES * 128;     // N*128
    float* abuf = tmpa + (size_t)N_NODES * 128;    // N*128
    float* pooled = abuf + (size_t)N_NODES * 128;  // 128*65
    int* ibase = (int*)(pooled + N_GRAPHS * (LATENT + 1));
    int* deg = ibase;                    // N
    int* cursor = deg + N_NODES;         // N
    int* eperm = cursor + N_NODES;       // E
    int* sperm = eperm + N_EDGES;        // E
    int* dperm = sperm + N_EDGES;        // E

    // CSR permutation (dst-sorted edge order)
    zero_i_kernel<<<(N_NODES + 255) / 256, 256, 0, stream>>>(deg, N_NODES);
    hist_kernel<<<(N_EDGES + 255) / 256, 256, 0, stream>>>(dsts, deg);
    prefix_kernel<<<1, 1024, 0, stream>>>(deg, cursor);
    scatter_kernel<<<(N_EDGES + 255) / 256, 256, 0, stream>>>(srcs, dsts, cursor, eperm, sperm,
                                                              dperm);
    // geometry in permuted order
    geom_kernel<<<(N_EDGES + 255) / 256, 256, 0, stream>>>(pos, ei, eperm, rbf, dirn);

    init_x_kernel<<<(N_NODES * HIDDEN + 255) / 256, 256, 0, stream>>>(z, embed, x);
    zero_f_kernel<<<(N_NODES * 384 + 255) / 256, 256, 0, stream>>>(vec, N_NODES * 384);

    for (int l = 0; l < 2; l++) {
        gemm_nn<128, 0><<<(N_NODES * 3 + 63) / 64, 256, 0, stream>>>(
            vec, Wv + (size_t)l * 128 * 128, nullptr, nullptr, vmix, N_NODES * 3);
        zero_f_kernel<<<(N_NODES * 128 + 255) / 256, 256, 0, stream>>>(dxb, N_NODES * 128);
        edge_fused<<<N_EDGES / 64, 256, 0, stream>>>(rbf, W_rbf + (size_t)l * 32 * 128, x, sperm,
                                                     dperm, W1 + (size_t)l * 128 * 128, dirn,
                                                     vmix, dxb, vec);
        gemm_nn<128, 2><<<(N_NODES + 63) / 64, 256, 0, stream>>>(
            dxb, Wo + (size_t)l * 128 * 128, nullptr, x, x, N_NODES);
    }

    gemm_nn<128, 0><<<(N_NODES * 3 + 63) / 64, 256, 0, stream>>>(vec, Wvec2, nullptr, nullptr,
                                                                 vmix, N_NODES * 3);
    vnorm_kernel<<<(N_NODES * HIDDEN + 255) / 256, 256, 0, stream>>>(vmix, dxb);
    gemm_nn<128, 1><<<(N_NODES + 63) / 64, 256, 0, stream>>>(x, W_a, b_a, nullptr, tmpa, N_NODES);
    gemm_nn<128, 6><<<(N_NODES + 63) / 64, 256, 0, stream>>>(dxb, W_a + 128 * 128, nullptr, tmpa,
                                                             abuf, N_NODES);

    zero_f_kernel<<<(N_GRAPHS * (LATENT + 1) + 255) / 256, 256, 0, stream>>>(
        pooled, N_GRAPHS * (LATENT + 1));
    out_pool_kernel<<<N_NODES, 128, 0, stream>>>(abuf, W_b, b_b, batch, pooled);
    finalize_kernel<<<(N_GRAPHS * (LATENT + 1) + 255) / 256, 256, 0, stream>>>(pooled, out);
}

// Round 4
// 685.872 us; speedup vs baseline: 1.4977x; 1.4977x over previous
//
#include <hip/hip_runtime.h>
#include <math.h>

#define N_NODES 10000
#define N_EDGES 160000
#define HIDDEN 128
#define NUM_RBF 32
#define LATENT 64
#define N_GRAPHS 128
#define CUTOFF 5.0f
#define EPS 1e-8f

typedef __attribute__((ext_vector_type(8))) short short8;
typedef __attribute__((ext_vector_type(4))) float f32x4;

__device__ __forceinline__ float silu(float v) { return v / (1.0f + expf(-v)); }

__device__ __forceinline__ unsigned short f2bf(float f) {
    union { float f; unsigned u; } v;
    v.f = f;
    unsigned r = v.u + 0x7FFFu + ((v.u >> 16) & 1u);  // RNE
    return (unsigned short)(r >> 16);
}
__device__ __forceinline__ float bf2f(unsigned short u) {
    union { unsigned u; float f; } v;
    v.u = ((unsigned)u) << 16;
    return v.f;
}

__global__ void zero_f_kernel(float* __restrict__ p, int n) {
    int i = blockIdx.x * blockDim.x + threadIdx.x;
    if (i < n) p[i] = 0.0f;
}
__global__ void zero_i_kernel(int* __restrict__ p, int n) {
    int i = blockIdx.x * blockDim.x + threadIdx.x;
    if (i < n) p[i] = 0;
}

__global__ void hist_kernel(const int* __restrict__ dst, int* __restrict__ deg) {
    int e = blockIdx.x * blockDim.x + threadIdx.x;
    if (e < N_EDGES) atomicAdd(&deg[dst[e]], 1);
}

__global__ void prefix_kernel(const int* __restrict__ deg, int* __restrict__ rowptr,
                              int* __restrict__ cursor) {
    __shared__ int part[1024];
    const int ITEMS = 10;
    int t = threadIdx.x;
    int base = t * ITEMS;
    int local[ITEMS];
    int s = 0;
#pragma unroll
    for (int j = 0; j < ITEMS; j++) {
        int idx = base + j;
        int v = (idx < N_NODES) ? deg[idx] : 0;
        local[j] = s;
        s += v;
    }
    part[t] = s;
    __syncthreads();
    for (int off = 1; off < 1024; off <<= 1) {
        int v = (t >= off) ? part[t - off] : 0;
        __syncthreads();
        part[t] += v;
        __syncthreads();
    }
    int base_sum = (t > 0) ? part[t - 1] : 0;
#pragma unroll
    for (int j = 0; j < ITEMS; j++) {
        int idx = base + j;
        if (idx < N_NODES) {
            rowptr[idx] = base_sum + local[j];
            cursor[idx] = base_sum + local[j];
        }
    }
    if (t == 1023) rowptr[N_NODES] = part[1023];
}

__global__ void scatter_kernel(const int* __restrict__ dst, int* __restrict__ cursor,
                               int* __restrict__ eperm) {
    int e = blockIdx.x * blockDim.x + threadIdx.x;
    if (e < N_EDGES) {
        int p = atomicAdd(&cursor[dst[e]], 1);
        eperm[p] = e;
    }
}

// per-edge geometry (original edge order): rbf (E x 32), dirn (E x 3)
__global__ void geom_kernel(const float* __restrict__ pos, const int* __restrict__ ei,
                            float* __restrict__ rbf, float* __restrict__ dirn) {
    int e = blockIdx.x * blockDim.x + threadIdx.x;
    if (e >= N_EDGES) return;
    int s = ei[e];
    int t = ei[N_EDGES + e];
    float dx = pos[t * 3 + 0] - pos[s * 3 + 0];
    float dy = pos[t * 3 + 1] - pos[s * 3 + 1];
    float dz = pos[t * 3 + 2] - pos[s * 3 + 2];
    float r = sqrtf(dx * dx + dy * dy + dz * dz + EPS);
    float inv = 1.0f / r;
    dirn[e * 3 + 0] = dx * inv;
    dirn[e * 3 + 1] = dy * inv;
    dirn[e * 3 + 2] = dz * inv;

    float e5 = expf(-CUTOFF);
    float span = 1.0f - e5;
    float b = (2.0f / NUM_RBF) * span;
    float beta = 1.0f / (b * b);
    float cut = (r < CUTOFF) ? 0.5f * (cosf((float)M_PI * r / CUTOFF) + 1.0f) : 0.0f;
    float er = expf(-r);
#pragma unroll
    for (int k = 0; k < NUM_RBF; k++) {
        float mean = e5 + span * ((float)k / (NUM_RBF - 1));
        float d = er - mean;
        rbf[e * NUM_RBF + k] = cut * expf(-beta * d * d);
    }
}

__global__ void init_x_kernel(const int* __restrict__ z, const float* __restrict__ embed,
                              float* __restrict__ x) {
    int i = blockIdx.x * blockDim.x + threadIdx.x;
    if (i < N_NODES * HIDDEN) {
        int n = i >> 7;
        int h = i & 127;
        x[i] = embed[z[n] * HIDDEN + h];
    }
}

// W1T[l][n][k] = bf16(W1[l][k][n]) for both layers
__global__ void w1t_kernel(const float* __restrict__ W1, unsigned short* __restrict__ W1T) {
    int i = blockIdx.x * blockDim.x + threadIdx.x;
    if (i >= 2 * 128 * 128) return;
    int l = i >> 14;
    int rem = i & 16383;
    int n = rem >> 7;
    int k = rem & 127;
    W1T[i] = f2bf(W1[l * 16384 + k * 128 + n]);
}

// ---------------- generic tiled fp32 GEMM: C = epi(A[MxK] @ W[Kx128]) ----------------
// EPI bits: 1=bias, 2=add Cin, 4=silu
template <int K, int EPI>
__global__ __launch_bounds__(256) void gemm_nn(const float* __restrict__ A,
                                               const float* __restrict__ W,
                                               const float* __restrict__ bias,
                                               const float* __restrict__ Cin,
                                               float* __restrict__ C, int M) {
    constexpr int STR = K + 4;
    __shared__ float As[64 * STR];
    int tid = threadIdx.x;
    int rg = tid >> 5;
    int cg = tid & 31;
    int row0 = blockIdx.x * 64;

    for (int idx = tid; idx < 64 * (K / 4); idx += 256) {
        int r = idx / (K / 4);
        int k4 = idx % (K / 4);
        float4 v = make_float4(0.f, 0.f, 0.f, 0.f);
        if (row0 + r < M) v = *(const float4*)(A + (size_t)(row0 + r) * K + k4 * 4);
        *(float4*)(As + r * STR + k4 * 4) = v;
    }
    __syncthreads();

    float acc[8][4];
#pragma unroll
    for (int i = 0; i < 8; i++)
#pragma unroll
        for (int j = 0; j < 4; j++) acc[i][j] = 0.f;

    const float* Wp = W + cg * 4;
#pragma unroll 4
    for (int k4 = 0; k4 < K / 4; k4++) {
        float4 w0 = *(const float4*)(Wp + (k4 * 4 + 0) * 128);
        float4 w1 = *(const float4*)(Wp + (k4 * 4 + 1) * 128);
        float4 w2 = *(const float4*)(Wp + (k4 * 4 + 2) * 128);
        float4 w3 = *(const float4*)(Wp + (k4 * 4 + 3) * 128);
#pragma unroll
        for (int i = 0; i < 8; i++) {
            float4 av = *(const float4*)(As + (rg * 8 + i) * STR + k4 * 4);
            acc[i][0] += av.x * w0.x + av.y * w1.x + av.z * w2.x + av.w * w3.x;
            acc[i][1] += av.x * w0.y + av.y * w1.y + av.z * w2.y + av.w * w3.y;
            acc[i][2] += av.x * w0.z + av.y * w1.z + av.z * w2.z + av.w * w3.z;
            acc[i][3] += av.x * w0.w + av.y * w1.w + av.z * w2.w + av.w * w3.w;
        }
    }

    float4 bv = make_float4(0.f, 0.f, 0.f, 0.f);
    if (EPI & 1) bv = *(const float4*)(bias + cg * 4);
#pragma unroll
    for (int i = 0; i < 8; i++) {
        int r = row0 + rg * 8 + i;
        if (r < M) {
            float4 o;
            o.x = acc[i][0] + bv.x;
            o.y = acc[i][1] + bv.y;
            o.z = acc[i][2] + bv.z;
            o.w = acc[i][3] + bv.w;
            if (EPI & 2) {
                float4 ci = *(const float4*)(Cin + (size_t)r * 128 + cg * 4);
                o.x += ci.x; o.y += ci.y; o.z += ci.z; o.w += ci.w;
            }
            if (EPI & 4) {
                o.x = silu(o.x); o.y = silu(o.y); o.z = silu(o.z); o.w = silu(o.w);
            }
            *(float4*)(C + (size_t)r * 128 + cg * 4) = o;
        }
    }
}

// ------------- edge kernel: VALU filt (K=32) -> t bf16 in LDS -> MFMA phi (K=128) -------------
// 64 edges/block, 256 threads = 4 waves. filt/phi stored bf16.
__global__ __launch_bounds__(256) void edge_mfma(
    const float* __restrict__ rbf, const float* __restrict__ Wrbf, const float* __restrict__ x,
    const int* __restrict__ srcs, const unsigned short* __restrict__ W1T,
    unsigned short* __restrict__ filt_out, unsigned short* __restrict__ phi_out) {
    // aliased LDS: phase1 rbf tile fp32 [64][36] (9216B); phase2+ t tile bf16 [64][136] (17408B)
    __shared__ __align__(16) char smem[64 * 136 * 2];
    float* Rs = (float*)smem;
    unsigned short* Ts = (unsigned short*)smem;
    __shared__ int s_src[64];

    int tid = threadIdx.x;
    int rg = tid >> 5;  // 0..7
    int cg = tid & 31;  // 0..31
    int row0 = blockIdx.x * 64;

    for (int idx = tid; idx < 64 * 8; idx += 256) {
        int r = idx >> 3;
        int k4 = idx & 7;
        *(float4*)(Rs + r * 36 + k4 * 4) =
            *(const float4*)(rbf + (size_t)(row0 + r) * 32 + k4 * 4);
    }
    if (tid < 64) s_src[tid] = srcs[row0 + tid];
    __syncthreads();

    // filt = rbf @ Wrbf (fp32 VALU, K=32); thread owns rows rg*8+i, cols cg*4..+3
    float fa[8][4];
#pragma unroll
    for (int i = 0; i < 8; i++)
#pragma unroll
        for (int j = 0; j < 4; j++) fa[i][j] = 0.f;
    {
        const float* Wp = Wrbf + cg * 4;
#pragma unroll
        for (int k4 = 0; k4 < 8; k4++) {
            float4 w0 = *(const float4*)(Wp + (k4 * 4 + 0) * 128);
            float4 w1 = *(const float4*)(Wp + (k4 * 4 + 1) * 128);
            float4 w2 = *(const float4*)(Wp + (k4 * 4 + 2) * 128);
            float4 w3 = *(const float4*)(Wp + (k4 * 4 + 3) * 128);
#pragma unroll
            for (int i = 0; i < 8; i++) {
                float4 av = *(const float4*)(Rs + (rg * 8 + i) * 36 + k4 * 4);
                fa[i][0] += av.x * w0.x + av.y * w1.x + av.z * w2.x + av.w * w3.x;
                fa[i][1] += av.x * w0.y + av.y * w1.y + av.z * w2.y + av.w * w3.y;
                fa[i][2] += av.x * w0.z + av.y * w1.z + av.z * w2.z + av.w * w3.z;
                fa[i][3] += av.x * w0.w + av.y * w1.w + av.z * w2.w + av.w * w3.w;
            }
        }
    }
    __syncthreads();  // everyone done reading Rs

    // t = filt * x[src] -> LDS bf16 [row][136]; also store filt bf16 to global
#pragma unroll
    for (int i = 0; i < 8; i++) {
        int r = rg * 8 + i;
        float4 xv = *(const float4*)(x + (size_t)s_src[r] * 128 + cg * 4);
        unsigned short tb[4];
        tb[0] = f2bf(fa[i][0] * xv.x);
        tb[1] = f2bf(fa[i][1] * xv.y);
        tb[2] = f2bf(fa[i][2] * xv.z);
        tb[3] = f2bf(fa[i][3] * xv.w);
        *(uint2*)(Ts + r * 136 + cg * 4) = *(uint2*)tb;
        unsigned short fb[4];
        fb[0] = f2bf(fa[i][0]);
        fb[1] = f2bf(fa[i][1]);
        fb[2] = f2bf(fa[i][2]);
        fb[3] = f2bf(fa[i][3]);
        *(uint2*)(filt_out + (size_t)(row0 + r) * 128 + cg * 4) = *(uint2*)fb;
    }
    __syncthreads();

    // phi = silu(t @ W1) via MFMA 16x16x32 bf16; wave w owns rows w*16..+15, 8 col-tiles
    int w = tid >> 6;
    int l = tid & 63;
    int c = l & 15;
    int q = l >> 4;
    const unsigned short* ap = Ts + (w * 16 + c) * 136 + q * 8;
    const unsigned short* bp = W1T + c * 128 + q * 8;

    f32x4 acc[8] = {};
#pragma unroll
    for (int s = 0; s < 4; s++) {
        short8 af = *(const short8*)(ap + s * 32);
#pragma unroll
        for (int t = 0; t < 8; t++) {
            short8 bf = *(const short8*)(bp + t * 2048 + s * 32);
            acc[t] = __builtin_amdgcn_mfma_f32_16x16x32_bf16(af, bf, acc[t], 0, 0, 0);
        }
    }

    // D layout: row = q*4 + r (within wave tile), col = t*16 + c
#pragma unroll
    for (int t = 0; t < 8; t++) {
#pragma unroll
        for (int r = 0; r < 4; r++) {
            int row = row0 + w * 16 + q * 4 + r;
            phi_out[(size_t)row * 128 + t * 16 + c] = f2bf(silu(acc[t][r]));
        }
    }
}

// ------------- CSR gather per dst node (bf16 filt/phi) -------------
__global__ void gather_kernel(const int* __restrict__ rowptr, const int* __restrict__ eperm,
                              const int* __restrict__ srcs, const unsigned short* __restrict__ filt,
                              const unsigned short* __restrict__ phi, const float* __restrict__ dirn,
                              const float* __restrict__ vmix, float* __restrict__ dxb,
                              float* __restrict__ vec) {
    int n = blockIdx.x;
    int h = threadIdx.x;
    int beg = rowptr[n];
    int end = rowptr[n + 1];
    float dx = 0.f, v0 = 0.f, v1 = 0.f, v2 = 0.f;
    for (int i = beg; i < end; i++) {
        int e = eperm[i];
        int s = srcs[e];
        float f = bf2f(filt[(size_t)e * 128 + h]);
        float p = bf2f(phi[(size_t)e * 128 + h]);
        float d0 = dirn[e * 3 + 0];
        float d1 = dirn[e * 3 + 1];
        float d2 = dirn[e * 3 + 2];
        dx += p;
        v0 += vmix[(size_t)(s * 3 + 0) * 128 + h] * f + p * d0;
        v1 += vmix[(size_t)(s * 3 + 1) * 128 + h] * f + p * d1;
        v2 += vmix[(size_t)(s * 3 + 2) * 128 + h] * f + p * d2;
    }
    dxb[(size_t)n * 128 + h] = dx;
    vec[(size_t)(n * 3 + 0) * 128 + h] += v0;
    vec[(size_t)(n * 3 + 1) * 128 + h] += v1;
    vec[(size_t)(n * 3 + 2) * 128 + h] += v2;
}

__global__ void vnorm_kernel(const float* __restrict__ v2, float* __restrict__ vnorm) {
    int i = blockIdx.x * blockDim.x + threadIdx.x;
    if (i >= N_NODES * HIDDEN) return;
    int n = i >> 7;
    int h = i & 127;
    float a = v2[(size_t)(n * 3 + 0) * 128 + h];
    float b = v2[(size_t)(n * 3 + 1) * 128 + h];
    float c = v2[(size_t)(n * 3 + 2) * 128 + h];
    vnorm[i] = sqrtf(a * a + b * b + c * c + EPS);
}

__global__ void out_pool_kernel(const float* __restrict__ a, const float* __restrict__ W_b,
                                const float* __restrict__ b_b, const int* __restrict__ batch,
                                float* __restrict__ pooled) {
    __shared__ float sa[HIDDEN];
    int n = blockIdx.x;
    int h = threadIdx.x;
    sa[h] = a[(size_t)n * 128 + h];
    __syncthreads();
    if (h < LATENT + 1) {
        float o = b_b[h];
        for (int j = 0; j < HIDDEN; j++) o += sa[j] * W_b[j * (LATENT + 1) + h];
        atomicAdd(&pooled[batch[n] * (LATENT + 1) + h], o);
    }
}

__global__ void finalize_kernel(const float* __restrict__ pooled, float* __restrict__ out) {
    int i = blockIdx.x * blockDim.x + threadIdx.x;
    if (i >= N_GRAPHS * (LATENT + 1)) return;
    int g = i / (LATENT + 1);
    int k = i % (LATENT + 1);
    float v = pooled[i];
    if (k < LATENT) {
        out[g * LATENT + k] = v;
    } else {
        v = fminf(fmaxf(v, -10.0f), 2.0f);
        out[N_GRAPHS * LATENT + g] = v;
    }
}

extern "C" void kernel_launch(void* const* d_in, const int* in_sizes, int n_in,
                              void* d_out, int out_size, void* d_ws, size_t ws_size,
                              hipStream_t stream) {
    const int* z = (const int*)d_in[0];
    const float* pos = (const float*)d_in[1];
    const int* batch = (const int*)d_in[2];
    const int* ei = (const int*)d_in[3];
    const float* embed = (const float*)d_in[4];
    const float* W_rbf = (const float*)d_in[5];
    const float* W1 = (const float*)d_in[6];
    const float* Wo = (const float*)d_in[7];
    const float* Wv = (const float*)d_in[8];
    const float* Wvec2 = (const float*)d_in[10];
    const float* W_a = (const float*)d_in[11];
    const float* b_a = (const float*)d_in[12];
    const float* W_b = (const float*)d_in[13];
    const float* b_b = (const float*)d_in[14];
    float* out = (float*)d_out;

    const int* srcs = ei;
    const int* dsts = ei + N_EDGES;

    float* ws = (float*)d_ws;
    float* rbf = ws;                               // E*32
    float* dirn = rbf + (size_t)N_EDGES * 32;      // E*3
    float* x = dirn + (size_t)N_EDGES * 3;         // N*128
    float* vec = x + (size_t)N_NODES * 128;        // N*384
    float* vmix = vec + (size_t)N_NODES * 384;     // N*384 (later reused as v2)
    float* dxb = vmix + (size_t)N_NODES * 384;     // N*128 (later reused as vnorm)
    float* tmpa = dxb + (size_t)N_NODES * 128;     // N*128
    float* abuf = tmpa + (size_t)N_NODES * 128;    // N*128
    float* pooled = abuf + (size_t)N_NODES * 128;  // 128*65
    unsigned short* filt = (unsigned short*)(pooled + N_GRAPHS * (LATENT + 1) + 4);
    unsigned short* phi = filt + (size_t)N_EDGES * 128;  // E*128 bf16
    unsigned short* W1T = phi + (size_t)N_EDGES * 128;   // 2*128*128 bf16
    int* ibase = (int*)(W1T + 2 * 128 * 128);
    int* deg = ibase;                   // N
    int* rowptr = deg + N_NODES;        // N+1
    int* cursor = rowptr + N_NODES + 1; // N
    int* eperm = cursor + N_NODES;      // E

    // CSR build (dst-sorted permutation) + geometry (original order) + weight prep
    zero_i_kernel<<<(N_NODES + 255) / 256, 256, 0, stream>>>(deg, N_NODES);
    hist_kernel<<<(N_EDGES + 255) / 256, 256, 0, stream>>>(dsts, deg);
    prefix_kernel<<<1, 1024, 0, stream>>>(deg, rowptr, cursor);
    scatter_kernel<<<(N_EDGES + 255) / 256, 256, 0, stream>>>(dsts, cursor, eperm);
    geom_kernel<<<(N_EDGES + 255) / 256, 256, 0, stream>>>(pos, ei, rbf, dirn);
    w1t_kernel<<<(2 * 128 * 128 + 255) / 256, 256, 0, stream>>>(W1, W1T);

    init_x_kernel<<<(N_NODES * HIDDEN + 255) / 256, 256, 0, stream>>>(z, embed, x);
    zero_f_kernel<<<(N_NODES * 384 + 255) / 256, 256, 0, stream>>>(vec, N_NODES * 384);

    for (int l = 0; l < 2; l++) {
        gemm_nn<128, 0><<<(N_NODES * 3 + 63) / 64, 256, 0, stream>>>(
            vec, Wv + (size_t)l * 128 * 128, nullptr, nullptr, vmix, N_NODES * 3);
        edge_mfma<<<N_EDGES / 64, 256, 0, stream>>>(rbf, W_rbf + (size_t)l * 32 * 128, x, srcs,
                                                    W1T + (size_t)l * 128 * 128, filt, phi);
        gather_kernel<<<N_NODES, 128, 0, stream>>>(rowptr, eperm, srcs, filt, phi, dirn, vmix,
                                                   dxb, vec);
        gemm_nn<128, 2><<<(N_NODES + 63) / 64, 256, 0, stream>>>(
            dxb, Wo + (size_t)l * 128 * 128, nullptr, x, x, N_NODES);
    }

    gemm_nn<128, 0><<<(N_NODES * 3 + 63) / 64, 256, 0, stream>>>(vec, Wvec2, nullptr, nullptr,
                                                                 vmix, N_NODES * 3);
    vnorm_kernel<<<(N_NODES * HIDDEN + 255) / 256, 256, 0, stream>>>(vmix, dxb);
    gemm_nn<128, 1><<<(N_NODES + 63) / 64, 256, 0, stream>>>(x, W_a, b_a, nullptr, tmpa, N_NODES);
    gemm_nn<128, 6><<<(N_NODES + 63) / 64, 256, 0, stream>>>(dxb, W_a + 128 * 128, nullptr, tmpa,
                                                             abuf, N_NODES);

    zero_f_kernel<<<(N_GRAPHS * (LATENT + 1) + 255) / 256, 256, 0, stream>>>(
        pooled, N_GRAPHS * (LATENT + 1));
    out_pool_kernel<<<N_NODES, 128, 0, stream>>>(abuf, W_b, b_b, batch, pooled);
    finalize_kernel<<<(N_GRAPHS * (LATENT + 1) + 255) / 256, 256, 0, stream>>>(pooled, out);
}

// Round 5
// 575.871 us; speedup vs baseline: 1.7838x; 1.1910x over previous
//
#include <hip/hip_runtime.h>
#include <math.h>

#define N_NODES 10000
#define N_EDGES 160000
#define HIDDEN 128
#define NUM_RBF 32
#define LATENT 64
#define N_GRAPHS 128
#define CUTOFF 5.0f
#define EPS 1e-8f

typedef __attribute__((ext_vector_type(8))) short short8;
typedef __attribute__((ext_vector_type(4))) float f32x4;
typedef unsigned short ushort_t;

__device__ __forceinline__ float silu(float v) { return v / (1.0f + expf(-v)); }

__device__ __forceinline__ ushort_t f2bf(float f) {
    union { float f; unsigned u; } v;
    v.f = f;
    unsigned r = v.u + 0x7FFFu + ((v.u >> 16) & 1u);  // RNE
    return (ushort_t)(r >> 16);
}
__device__ __forceinline__ float bf2f(ushort_t u) {
    union { unsigned u; float f; } v;
    v.u = ((unsigned)u) << 16;
    return v.f;
}

__global__ void zero_f_kernel(float* __restrict__ p, int n) {
    int i = blockIdx.x * blockDim.x + threadIdx.x;
    if (i < n) p[i] = 0.0f;
}
__global__ void zero_i_kernel(int* __restrict__ p, int n) {
    int i = blockIdx.x * blockDim.x + threadIdx.x;
    if (i < n) p[i] = 0;
}

__global__ void hist_kernel(const int* __restrict__ dst, int* __restrict__ deg) {
    int e = blockIdx.x * blockDim.x + threadIdx.x;
    if (e < N_EDGES) atomicAdd(&deg[dst[e]], 1);
}

__global__ void prefix_kernel(const int* __restrict__ deg, int* __restrict__ rowptr,
                              int* __restrict__ cursor) {
    __shared__ int part[1024];
    const int ITEMS = 10;
    int t = threadIdx.x;
    int base = t * ITEMS;
    int local[ITEMS];
    int s = 0;
#pragma unroll
    for (int j = 0; j < ITEMS; j++) {
        int idx = base + j;
        int v = (idx < N_NODES) ? deg[idx] : 0;
        local[j] = s;
        s += v;
    }
    part[t] = s;
    __syncthreads();
    for (int off = 1; off < 1024; off <<= 1) {
        int v = (t >= off) ? part[t - off] : 0;
        __syncthreads();
        part[t] += v;
        __syncthreads();
    }
    int base_sum = (t > 0) ? part[t - 1] : 0;
#pragma unroll
    for (int j = 0; j < ITEMS; j++) {
        int idx = base + j;
        if (idx < N_NODES) {
            rowptr[idx] = base_sum + local[j];
            cursor[idx] = base_sum + local[j];
        }
    }
    if (t == 1023) rowptr[N_NODES] = part[1023];
}

__global__ void scatter_kernel(const int* __restrict__ dst, int* __restrict__ cursor,
                               int* __restrict__ eperm) {
    int e = blockIdx.x * blockDim.x + threadIdx.x;
    if (e < N_EDGES) {
        int p = atomicAdd(&cursor[dst[e]], 1);
        eperm[p] = e;
    }
}

// per-edge geometry (original edge order): rbf bf16 (E x 32), dirn fp32 (E x 3)
__global__ void geom_kernel(const float* __restrict__ pos, const int* __restrict__ ei,
                            ushort_t* __restrict__ rbf16, float* __restrict__ dirn) {
    int e = blockIdx.x * blockDim.x + threadIdx.x;
    if (e >= N_EDGES) return;
    int s = ei[e];
    int t = ei[N_EDGES + e];
    float dx = pos[t * 3 + 0] - pos[s * 3 + 0];
    float dy = pos[t * 3 + 1] - pos[s * 3 + 1];
    float dz = pos[t * 3 + 2] - pos[s * 3 + 2];
    float r = sqrtf(dx * dx + dy * dy + dz * dz + EPS);
    float inv = 1.0f / r;
    dirn[e * 3 + 0] = dx * inv;
    dirn[e * 3 + 1] = dy * inv;
    dirn[e * 3 + 2] = dz * inv;

    float e5 = expf(-CUTOFF);
    float span = 1.0f - e5;
    float b = (2.0f / NUM_RBF) * span;
    float beta = 1.0f / (b * b);
    float cut = (r < CUTOFF) ? 0.5f * (cosf((float)M_PI * r / CUTOFF) + 1.0f) : 0.0f;
    float er = expf(-r);
#pragma unroll
    for (int k = 0; k < NUM_RBF; k++) {
        float mean = e5 + span * ((float)k / (NUM_RBF - 1));
        float d = er - mean;
        rbf16[(size_t)e * 32 + k] = f2bf(cut * expf(-beta * d * d));
    }
}

__global__ void init_x_kernel(const int* __restrict__ z, const float* __restrict__ embed,
                              float* __restrict__ x) {
    int i = blockIdx.x * blockDim.x + threadIdx.x;
    if (i < N_NODES * HIDDEN) {
        int n = i >> 7;
        int h = i & 127;
        x[i] = embed[z[n] * HIDDEN + h];
    }
}

// W1T[l][n][k] = bf16(W1[l][k][n]); WrbfT[l][n][k] = bf16(Wrbf[l][k][n])
__global__ void wprep_kernel(const float* __restrict__ W1, const float* __restrict__ Wrbf,
                             ushort_t* __restrict__ W1T, ushort_t* __restrict__ WrbfT) {
    int i = blockIdx.x * blockDim.x + threadIdx.x;
    if (i < 2 * 128 * 128) {
        int l = i >> 14;
        int rem = i & 16383;
        int n = rem >> 7;
        int k = rem & 127;
        W1T[i] = f2bf(W1[l * 16384 + k * 128 + n]);
    }
    if (i < 2 * 128 * 32) {
        int l = i / (128 * 32);
        int rem = i % (128 * 32);
        int n = rem >> 5;
        int k = rem & 31;
        WrbfT[i] = f2bf(Wrbf[l * 4096 + k * 128 + n]);
    }
}

// ---------------- generic tiled fp32 GEMM: C = epi(A[MxK] @ W[Kx128]) ----------------
// EPI bits: 1=bias, 2=add Cin, 4=silu, 8=bf16 output
template <int K, int EPI>
__global__ __launch_bounds__(256) void gemm_nn(const float* __restrict__ A,
                                               const float* __restrict__ W,
                                               const float* __restrict__ bias,
                                               const float* __restrict__ Cin,
                                               float* __restrict__ C, int M) {
    constexpr int STR = K + 4;
    __shared__ float As[64 * STR];
    int tid = threadIdx.x;
    int rg = tid >> 5;
    int cg = tid & 31;
    int row0 = blockIdx.x * 64;

    for (int idx = tid; idx < 64 * (K / 4); idx += 256) {
        int r = idx / (K / 4);
        int k4 = idx % (K / 4);
        float4 v = make_float4(0.f, 0.f, 0.f, 0.f);
        if (row0 + r < M) v = *(const float4*)(A + (size_t)(row0 + r) * K + k4 * 4);
        *(float4*)(As + r * STR + k4 * 4) = v;
    }
    __syncthreads();

    float acc[8][4];
#pragma unroll
    for (int i = 0; i < 8; i++)
#pragma unroll
        for (int j = 0; j < 4; j++) acc[i][j] = 0.f;

    const float* Wp = W + cg * 4;
#pragma unroll 4
    for (int k4 = 0; k4 < K / 4; k4++) {
        float4 w0 = *(const float4*)(Wp + (k4 * 4 + 0) * 128);
        float4 w1 = *(const float4*)(Wp + (k4 * 4 + 1) * 128);
        float4 w2 = *(const float4*)(Wp + (k4 * 4 + 2) * 128);
        float4 w3 = *(const float4*)(Wp + (k4 * 4 + 3) * 128);
#pragma unroll
        for (int i = 0; i < 8; i++) {
            float4 av = *(const float4*)(As + (rg * 8 + i) * STR + k4 * 4);
            acc[i][0] += av.x * w0.x + av.y * w1.x + av.z * w2.x + av.w * w3.x;
            acc[i][1] += av.x * w0.y + av.y * w1.y + av.z * w2.y + av.w * w3.y;
            acc[i][2] += av.x * w0.z + av.y * w1.z + av.z * w2.z + av.w * w3.z;
            acc[i][3] += av.x * w0.w + av.y * w1.w + av.z * w2.w + av.w * w3.w;
        }
    }

    float4 bv = make_float4(0.f, 0.f, 0.f, 0.f);
    if (EPI & 1) bv = *(const float4*)(bias + cg * 4);
#pragma unroll
    for (int i = 0; i < 8; i++) {
        int r = row0 + rg * 8 + i;
        if (r < M) {
            float4 o;
            o.x = acc[i][0] + bv.x;
            o.y = acc[i][1] + bv.y;
            o.z = acc[i][2] + bv.z;
            o.w = acc[i][3] + bv.w;
            if (EPI & 2) {
                float4 ci = *(const float4*)(Cin + (size_t)r * 128 + cg * 4);
                o.x += ci.x; o.y += ci.y; o.z += ci.z; o.w += ci.w;
            }
            if (EPI & 4) {
                o.x = silu(o.x); o.y = silu(o.y); o.z = silu(o.z); o.w = silu(o.w);
            }
            if (EPI & 8) {
                ushort_t ob[4] = {f2bf(o.x), f2bf(o.y), f2bf(o.z), f2bf(o.w)};
                *(uint2*)((ushort_t*)C + (size_t)r * 128 + cg * 4) = *(uint2*)ob;
            } else {
                *(float4*)(C + (size_t)r * 128 + cg * 4) = o;
            }
        }
    }
}

// ------------- edge kernel: MFMA filt (K=32) -> t bf16 LDS -> MFMA phi (K=128) -------------
// 64 edges/block, 256 threads = 4 waves; wave w owns rows w*16..w*16+15 end-to-end.
__global__ __launch_bounds__(256) void edge_mfma(
    const ushort_t* __restrict__ rbf16, const ushort_t* __restrict__ WrbfT,
    const float* __restrict__ x, const int* __restrict__ srcs,
    const ushort_t* __restrict__ W1T, ushort_t* __restrict__ filt_out,
    ushort_t* __restrict__ phi_out) {
    __shared__ ushort_t Rs[64 * 40];   // rbf tile (A-frags), stride 40 (80B, 16B-aligned rows)
    __shared__ ushort_t Xs[64 * 136];  // x[src] tile bf16; later reused for phi bf16
    __shared__ ushort_t Ts[64 * 136];  // t tile bf16; later reused for filt bf16

    int tid = threadIdx.x;
    int row0 = blockIdx.x * 64;
    int w = tid >> 6;       // wave 0..3
    int lane = tid & 63;
    int c = lane & 15;      // MFMA col-lane / A-row-lane
    int q = lane >> 4;      // quad 0..3

    // stage rbf tile: 1 uint4 (8 bf16) per thread
    {
        int r = tid >> 2;
        int c8 = tid & 3;
        *(uint4*)(Rs + r * 40 + c8 * 8) =
            *(const uint4*)(rbf16 + (size_t)(row0 + r) * 32 + c8 * 8);
    }
    // stage x[src] tile bf16: 4 threads per row, 8 float4 each
    {
        int r = tid >> 2;
        int sr = srcs[row0 + r];
        const float* xp = x + (size_t)sr * 128;
#pragma unroll
        for (int u = 0; u < 8; u++) {
            int seg = (tid & 3) * 32 + u * 4;
            float4 v = *(const float4*)(xp + seg);
            ushort_t b4[4] = {f2bf(v.x), f2bf(v.y), f2bf(v.z), f2bf(v.w)};
            *(uint2*)(Xs + r * 136 + seg) = *(uint2*)b4;
        }
    }
    __syncthreads();

    // filt = rbf @ Wrbf via MFMA (K=32: single step per col-tile)
    f32x4 facc[8];
    {
        short8 af = *(const short8*)(Rs + (w * 16 + c) * 40 + q * 8);
#pragma unroll
        for (int t8 = 0; t8 < 8; t8++) {
            short8 bfr = *(const short8*)(WrbfT + (size_t)(t8 * 16 + c) * 32 + q * 8);
            f32x4 z = {};
            facc[t8] = __builtin_amdgcn_mfma_f32_16x16x32_bf16(af, bfr, z, 0, 0, 0);
        }
    }

    // epilogue A: t = filt * x  (D layout: row=w*16+q*4+r, col=t8*16+c) -> Ts
#pragma unroll
    for (int t8 = 0; t8 < 8; t8++) {
#pragma unroll
        for (int r = 0; r < 4; r++) {
            int row = w * 16 + q * 4 + r;
            int col = t8 * 16 + c;
            float xv = bf2f(Xs[row * 136 + col]);
            Ts[row * 136 + col] = f2bf(facc[t8][r] * xv);
        }
    }
    __syncthreads();

    // phi = silu(t @ W1) via MFMA, K=128
    f32x4 pacc[8] = {};
    const ushort_t* ap = Ts + (w * 16 + c) * 136 + q * 8;
#pragma unroll
    for (int s = 0; s < 4; s++) {
        short8 af = *(const short8*)(ap + s * 32);
#pragma unroll
        for (int t8 = 0; t8 < 8; t8++) {
            short8 bfr = *(const short8*)(W1T + (size_t)(t8 * 16 + c) * 128 + s * 32 + q * 8);
            pacc[t8] = __builtin_amdgcn_mfma_f32_16x16x32_bf16(af, bfr, pacc[t8], 0, 0, 0);
        }
    }

    // epilogue B (wave-private rows): phi -> Xs, filt -> Ts
#pragma unroll
    for (int t8 = 0; t8 < 8; t8++) {
#pragma unroll
        for (int r = 0; r < 4; r++) {
            int row = w * 16 + q * 4 + r;
            int col = t8 * 16 + c;
            Xs[row * 136 + col] = f2bf(silu(pacc[t8][r]));
            Ts[row * 136 + col] = f2bf(facc[t8][r]);
        }
    }
    __syncthreads();

    // coalesced flush: 64 rows x 16 uint4 chunks each
    for (int idx = tid; idx < 64 * 16; idx += 256) {
        int r = idx >> 4;
        int c8 = idx & 15;
        *(uint4*)(phi_out + (size_t)(row0 + r) * 128 + c8 * 8) = *(uint4*)(Xs + r * 136 + c8 * 8);
        *(uint4*)(filt_out + (size_t)(row0 + r) * 128 + c8 * 8) = *(uint4*)(Ts + r * 136 + c8 * 8);
    }
}

// ------------- CSR gather per dst node (bf16 filt/phi/vmix) -------------
__global__ void gather_kernel(const int* __restrict__ rowptr, const int* __restrict__ eperm,
                              const int* __restrict__ srcs, const ushort_t* __restrict__ filt,
                              const ushort_t* __restrict__ phi, const float* __restrict__ dirn,
                              const ushort_t* __restrict__ vmix, float* __restrict__ dxb,
                              float* __restrict__ vec) {
    int n = blockIdx.x;
    int h = threadIdx.x;
    int beg = rowptr[n];
    int end = rowptr[n + 1];
    float dx = 0.f, v0 = 0.f, v1 = 0.f, v2 = 0.f;
    for (int i = beg; i < end; i++) {
        int e = eperm[i];
        int s = srcs[e];
        float f = bf2f(filt[(size_t)e * 128 + h]);
        float p = bf2f(phi[(size_t)e * 128 + h]);
        float d0 = dirn[e * 3 + 0];
        float d1 = dirn[e * 3 + 1];
        float d2 = dirn[e * 3 + 2];
        const ushort_t* vm = vmix + (size_t)s * 384 + h;
        dx += p;
        v0 += bf2f(vm[0]) * f + p * d0;
        v1 += bf2f(vm[128]) * f + p * d1;
        v2 += bf2f(vm[256]) * f + p * d2;
    }
    dxb[(size_t)n * 128 + h] = dx;
    vec[(size_t)(n * 3 + 0) * 128 + h] += v0;
    vec[(size_t)(n * 3 + 1) * 128 + h] += v1;
    vec[(size_t)(n * 3 + 2) * 128 + h] += v2;
}

__global__ void vnorm_kernel(const float* __restrict__ v2, float* __restrict__ vnorm) {
    int i = blockIdx.x * blockDim.x + threadIdx.x;
    if (i >= N_NODES * HIDDEN) return;
    int n = i >> 7;
    int h = i & 127;
    float a = v2[(size_t)(n * 3 + 0) * 128 + h];
    float b = v2[(size_t)(n * 3 + 1) * 128 + h];
    float c = v2[(size_t)(n * 3 + 2) * 128 + h];
    vnorm[i] = sqrtf(a * a + b * b + c * c + EPS);
}

__global__ void out_pool_kernel(const float* __restrict__ a, const float* __restrict__ W_b,
                                const float* __restrict__ b_b, const int* __restrict__ batch,
                                float* __restrict__ pooled) {
    __shared__ float sa[HIDDEN];
    int n = blockIdx.x;
    int h = threadIdx.x;
    sa[h] = a[(size_t)n * 128 + h];
    __syncthreads();
    if (h < LATENT + 1) {
        float o = b_b[h];
        for (int j = 0; j < HIDDEN; j++) o += sa[j] * W_b[j * (LATENT + 1) + h];
        atomicAdd(&pooled[batch[n] * (LATENT + 1) + h], o);
    }
}

__global__ void finalize_kernel(const float* __restrict__ pooled, float* __restrict__ out) {
    int i = blockIdx.x * blockDim.x + threadIdx.x;
    if (i >= N_GRAPHS * (LATENT + 1)) return;
    int g = i / (LATENT + 1);
    int k = i % (LATENT + 1);
    float v = pooled[i];
    if (k < LATENT) {
        out[g * LATENT + k] = v;
    } else {
        v = fminf(fmaxf(v, -10.0f), 2.0f);
        out[N_GRAPHS * LATENT + g] = v;
    }
}

extern "C" void kernel_launch(void* const* d_in, const int* in_sizes, int n_in,
                              void* d_out, int out_size, void* d_ws, size_t ws_size,
                              hipStream_t stream) {
    const int* z = (const int*)d_in[0];
    const float* pos = (const float*)d_in[1];
    const int* batch = (const int*)d_in[2];
    const int* ei = (const int*)d_in[3];
    const float* embed = (const float*)d_in[4];
    const float* W_rbf = (const float*)d_in[5];
    const float* W1 = (const float*)d_in[6];
    const float* Wo = (const float*)d_in[7];
    const float* Wv = (const float*)d_in[8];
    const float* Wvec2 = (const float*)d_in[10];
    const float* W_a = (const float*)d_in[11];
    const float* b_a = (const float*)d_in[12];
    const float* W_b = (const float*)d_in[13];
    const float* b_b = (const float*)d_in[14];
    float* out = (float*)d_out;

    const int* srcs = ei;
    const int* dsts = ei + N_EDGES;

    float* ws = (float*)d_ws;
    float* dirn = ws;                              // E*3
    float* x = dirn + (size_t)N_EDGES * 3;         // N*128
    float* vec = x + (size_t)N_NODES * 128;        // N*384
    float* vbuf = vec + (size_t)N_NODES * 384;     // N*384 (v2 fp32)
    float* dxb = vbuf + (size_t)N_NODES * 384;     // N*128 (later vnorm)
    float* tmpa = dxb + (size_t)N_NODES * 128;     // N*128
    float* abuf = tmpa + (size_t)N_NODES * 128;    // N*128
    float* pooled = abuf + (size_t)N_NODES * 128;  // 128*65 (+pad)
    ushort_t* rbf16 = (ushort_t*)(pooled + N_GRAPHS * (LATENT + 1) + 16);
    ushort_t* vmix16 = rbf16 + (size_t)N_EDGES * 32;   // N*384
    ushort_t* filt = vmix16 + (size_t)N_NODES * 384;   // E*128
    ushort_t* phi = filt + (size_t)N_EDGES * 128;      // E*128
    ushort_t* W1T = phi + (size_t)N_EDGES * 128;       // 2*128*128
    ushort_t* WrbfT = W1T + 2 * 128 * 128;             // 2*128*32
    int* ibase = (int*)(WrbfT + 2 * 128 * 32);
    int* deg = ibase;                    // N
    int* rowptr = deg + N_NODES;         // N+1
    int* cursor = rowptr + N_NODES + 1;  // N
    int* eperm = cursor + N_NODES;       // E

    // CSR build + geometry + weight prep
    zero_i_kernel<<<(N_NODES + 255) / 256, 256, 0, stream>>>(deg, N_NODES);
    hist_kernel<<<(N_EDGES + 255) / 256, 256, 0, stream>>>(dsts, deg);
    prefix_kernel<<<1, 1024, 0, stream>>>(deg, rowptr, cursor);
    scatter_kernel<<<(N_EDGES + 255) / 256, 256, 0, stream>>>(dsts, cursor, eperm);
    geom_kernel<<<(N_EDGES + 255) / 256, 256, 0, stream>>>(pos, ei, rbf16, dirn);
    wprep_kernel<<<(2 * 128 * 128 + 255) / 256, 256, 0, stream>>>(W1, W_rbf, W1T, WrbfT);

    init_x_kernel<<<(N_NODES * HIDDEN + 255) / 256, 256, 0, stream>>>(z, embed, x);
    zero_f_kernel<<<(N_NODES * 384 + 255) / 256, 256, 0, stream>>>(vec, N_NODES * 384);

    for (int l = 0; l < 2; l++) {
        // vmix16 = bf16(vec @ Wv[l])  (M = 30000)
        gemm_nn<128, 8><<<(N_NODES * 3 + 63) / 64, 256, 0, stream>>>(
            vec, Wv + (size_t)l * 128 * 128, nullptr, nullptr, (float*)vmix16, N_NODES * 3);
        edge_mfma<<<N_EDGES / 64, 256, 0, stream>>>(rbf16, WrbfT + (size_t)l * 128 * 32, x, srcs,
                                                    W1T + (size_t)l * 128 * 128, filt, phi);
        gather_kernel<<<N_NODES, 128, 0, stream>>>(rowptr, eperm, srcs, filt, phi, dirn, vmix16,
                                                   dxb, vec);
        gemm_nn<128, 2><<<(N_NODES + 63) / 64, 256, 0, stream>>>(
            dxb, Wo + (size_t)l * 128 * 128, nullptr, x, x, N_NODES);
    }

    gemm_nn<128, 0><<<(N_NODES * 3 + 63) / 64, 256, 0, stream>>>(vec, Wvec2, nullptr, nullptr,
                                                                 vbuf, N_NODES * 3);
    vnorm_kernel<<<(N_NODES * HIDDEN + 255) / 256, 256, 0, stream>>>(vbuf, dxb);
    gemm_nn<128, 1><<<(N_NODES + 63) / 64, 256, 0, stream>>>(x, W_a, b_a, nullptr, tmpa, N_NODES);
    gemm_nn<128, 6><<<(N_NODES + 63) / 64, 256, 0, stream>>>(dxb, W_a + 128 * 128, nullptr, tmpa,
                                                             abuf, N_NODES);

    zero_f_kernel<<<(N_GRAPHS * (LATENT + 1) + 255) / 256, 256, 0, stream>>>(
        pooled, N_GRAPHS * (LATENT + 1));
    out_pool_kernel<<<N_NODES, 128, 0, stream>>>(abuf, W_b, b_b, batch, pooled);
    finalize_kernel<<<(N_GRAPHS * (LATENT + 1) + 255) / 256, 256, 0, stream>>>(pooled, out);
}

// Round 6
// 552.882 us; speedup vs baseline: 1.8579x; 1.0416x over previous
//
#include <hip/hip_runtime.h>
#include <math.h>

#define N_NODES 10000
#define N_EDGES 160000
#define HIDDEN 128
#define NUM_RBF 32
#define LATENT 64
#define N_GRAPHS 128
#define CUTOFF 5.0f
#define EPS 1e-8f

typedef __attribute__((ext_vector_type(8))) short short8;
typedef __attribute__((ext_vector_type(4))) float f32x4;
typedef unsigned short ushort_t;

__device__ __forceinline__ float fast_silu(float v) {
    return v * __builtin_amdgcn_rcpf(1.0f + __expf(-v));
}

__device__ __forceinline__ ushort_t f2bf(float f) {
    union { float f; unsigned u; } v;
    v.f = f;
    unsigned r = v.u + 0x7FFFu + ((v.u >> 16) & 1u);  // RNE
    return (ushort_t)(r >> 16);
}
__device__ __forceinline__ float bf2f(ushort_t u) {
    union { unsigned u; float f; } v;
    v.u = ((unsigned)u) << 16;
    return v.f;
}

__global__ void zero_f_kernel(float* __restrict__ p, int n) {
    int i = blockIdx.x * blockDim.x + threadIdx.x;
    if (i < n) p[i] = 0.0f;
}
__global__ void zero_i_kernel(int* __restrict__ p, int n) {
    int i = blockIdx.x * blockDim.x + threadIdx.x;
    if (i < n) p[i] = 0;
}

__global__ void hist_kernel(const int* __restrict__ dst, int* __restrict__ deg) {
    int e = blockIdx.x * blockDim.x + threadIdx.x;
    if (e < N_EDGES) atomicAdd(&deg[dst[e]], 1);
}

__global__ void prefix_kernel(const int* __restrict__ deg, int* __restrict__ cursor) {
    __shared__ int part[1024];
    const int ITEMS = 10;
    int t = threadIdx.x;
    int base = t * ITEMS;
    int local[ITEMS];
    int s = 0;
#pragma unroll
    for (int j = 0; j < ITEMS; j++) {
        int idx = base + j;
        int v = (idx < N_NODES) ? deg[idx] : 0;
        local[j] = s;
        s += v;
    }
    part[t] = s;
    __syncthreads();
    for (int off = 1; off < 1024; off <<= 1) {
        int v = (t >= off) ? part[t - off] : 0;
        __syncthreads();
        part[t] += v;
        __syncthreads();
    }
    int base_sum = (t > 0) ? part[t - 1] : 0;
#pragma unroll
    for (int j = 0; j < ITEMS; j++) {
        int idx = base + j;
        if (idx < N_NODES) cursor[idx] = base_sum + local[j];
    }
}

// dst-sorted permutation: sperm[p]=src, dperm[p]=dst, eperm[p]=e
__global__ void scatter_kernel(const int* __restrict__ src, const int* __restrict__ dst,
                               int* __restrict__ cursor, int* __restrict__ eperm,
                               int* __restrict__ sperm, int* __restrict__ dperm) {
    int e = blockIdx.x * blockDim.x + threadIdx.x;
    if (e < N_EDGES) {
        int d = dst[e];
        int p = atomicAdd(&cursor[d], 1);
        eperm[p] = e;
        sperm[p] = src[e];
        dperm[p] = d;
    }
}

// geometry in PERMUTED (dst-sorted) order: rbf bf16 (E x 32), dirn fp32 (E x 3)
__global__ void geom_kernel(const float* __restrict__ pos, const int* __restrict__ ei,
                            const int* __restrict__ eperm, ushort_t* __restrict__ rbf16,
                            float* __restrict__ dirn) {
    int i = blockIdx.x * blockDim.x + threadIdx.x;
    if (i >= N_EDGES) return;
    int e = eperm[i];
    int s = ei[e];
    int t = ei[N_EDGES + e];
    float dx = pos[t * 3 + 0] - pos[s * 3 + 0];
    float dy = pos[t * 3 + 1] - pos[s * 3 + 1];
    float dz = pos[t * 3 + 2] - pos[s * 3 + 2];
    float r = sqrtf(dx * dx + dy * dy + dz * dz + EPS);
    float inv = 1.0f / r;
    dirn[i * 3 + 0] = dx * inv;
    dirn[i * 3 + 1] = dy * inv;
    dirn[i * 3 + 2] = dz * inv;

    float e5 = __expf(-CUTOFF);
    float span = 1.0f - e5;
    float b = (2.0f / NUM_RBF) * span;
    float beta = 1.0f / (b * b);
    float cut = (r < CUTOFF) ? 0.5f * (__cosf((float)M_PI * r / CUTOFF) + 1.0f) : 0.0f;
    float er = __expf(-r);
#pragma unroll
    for (int k = 0; k < NUM_RBF; k++) {
        float mean = e5 + span * ((float)k / (NUM_RBF - 1));
        float d = er - mean;
        rbf16[(size_t)i * 32 + k] = f2bf(cut * __expf(-beta * d * d));
    }
}

__global__ void init_x_kernel(const int* __restrict__ z, const float* __restrict__ embed,
                              float* __restrict__ x) {
    int i = blockIdx.x * blockDim.x + threadIdx.x;
    if (i < N_NODES * HIDDEN) {
        int n = i >> 7;
        int h = i & 127;
        x[i] = embed[z[n] * HIDDEN + h];
    }
}

// W1T[l][n][k] = bf16(W1[l][k][n]); WrbfT[l][n][k] = bf16(Wrbf[l][k][n])
__global__ void wprep_kernel(const float* __restrict__ W1, const float* __restrict__ Wrbf,
                             ushort_t* __restrict__ W1T, ushort_t* __restrict__ WrbfT) {
    int i = blockIdx.x * blockDim.x + threadIdx.x;
    if (i < 2 * 128 * 128) {
        int l = i >> 14;
        int rem = i & 16383;
        int n = rem >> 7;
        int k = rem & 127;
        W1T[i] = f2bf(W1[l * 16384 + k * 128 + n]);
    }
    if (i < 2 * 128 * 32) {
        int l = i / (128 * 32);
        int rem = i % (128 * 32);
        int n = rem >> 5;
        int k = rem & 31;
        WrbfT[i] = f2bf(Wrbf[l * 4096 + k * 128 + n]);
    }
}

// ---------------- generic tiled fp32 GEMM: C = epi(A[MxK] @ W[Kx128]) ----------------
// EPI bits: 1=bias, 2=add Cin, 4=silu, 8=bf16 output
template <int K, int EPI>
__global__ __launch_bounds__(256) void gemm_nn(const float* __restrict__ A,
                                               const float* __restrict__ W,
                                               const float* __restrict__ bias,
                                               const float* __restrict__ Cin,
                                               float* __restrict__ C, int M) {
    constexpr int STR = K + 4;
    __shared__ float As[64 * STR];
    int tid = threadIdx.x;
    int rg = tid >> 5;
    int cg = tid & 31;
    int row0 = blockIdx.x * 64;

    for (int idx = tid; idx < 64 * (K / 4); idx += 256) {
        int r = idx / (K / 4);
        int k4 = idx % (K / 4);
        float4 v = make_float4(0.f, 0.f, 0.f, 0.f);
        if (row0 + r < M) v = *(const float4*)(A + (size_t)(row0 + r) * K + k4 * 4);
        *(float4*)(As + r * STR + k4 * 4) = v;
    }
    __syncthreads();

    float acc[8][4];
#pragma unroll
    for (int i = 0; i < 8; i++)
#pragma unroll
        for (int j = 0; j < 4; j++) acc[i][j] = 0.f;

    const float* Wp = W + cg * 4;
#pragma unroll 4
    for (int k4 = 0; k4 < K / 4; k4++) {
        float4 w0 = *(const float4*)(Wp + (k4 * 4 + 0) * 128);
        float4 w1 = *(const float4*)(Wp + (k4 * 4 + 1) * 128);
        float4 w2 = *(const float4*)(Wp + (k4 * 4 + 2) * 128);
        float4 w3 = *(const float4*)(Wp + (k4 * 4 + 3) * 128);
#pragma unroll
        for (int i = 0; i < 8; i++) {
            float4 av = *(const float4*)(As + (rg * 8 + i) * STR + k4 * 4);
            acc[i][0] += av.x * w0.x + av.y * w1.x + av.z * w2.x + av.w * w3.x;
            acc[i][1] += av.x * w0.y + av.y * w1.y + av.z * w2.y + av.w * w3.y;
            acc[i][2] += av.x * w0.z + av.y * w1.z + av.z * w2.z + av.w * w3.z;
            acc[i][3] += av.x * w0.w + av.y * w1.w + av.z * w2.w + av.w * w3.w;
        }
    }

    float4 bv = make_float4(0.f, 0.f, 0.f, 0.f);
    if (EPI & 1) bv = *(const float4*)(bias + cg * 4);
#pragma unroll
    for (int i = 0; i < 8; i++) {
        int r = row0 + rg * 8 + i;
        if (r < M) {
            float4 o;
            o.x = acc[i][0] + bv.x;
            o.y = acc[i][1] + bv.y;
            o.z = acc[i][2] + bv.z;
            o.w = acc[i][3] + bv.w;
            if (EPI & 2) {
                float4 ci = *(const float4*)(Cin + (size_t)r * 128 + cg * 4);
                o.x += ci.x; o.y += ci.y; o.z += ci.z; o.w += ci.w;
            }
            if (EPI & 4) {
                o.x = fast_silu(o.x); o.y = fast_silu(o.y);
                o.z = fast_silu(o.z); o.w = fast_silu(o.w);
            }
            if (EPI & 8) {
                ushort_t ob[4] = {f2bf(o.x), f2bf(o.y), f2bf(o.z), f2bf(o.w)};
                *(uint2*)((ushort_t*)C + (size_t)r * 128 + cg * 4) = *(uint2*)ob;
            } else {
                *(float4*)(C + (size_t)r * 128 + cg * 4) = o;
            }
        }
    }
}

// ------- fused edge kernel: MFMA filt -> t -> MFMA phi -> column-parallel segmented scatter -------
// 64 dst-sorted edges/block, 256 threads = 4 waves.
__global__ __launch_bounds__(256) void edge_fused(
    const ushort_t* __restrict__ rbf16, const ushort_t* __restrict__ WrbfT,
    const float* __restrict__ x, const int* __restrict__ sperm, const int* __restrict__ dperm,
    const ushort_t* __restrict__ W1T, const float* __restrict__ dirn,
    const ushort_t* __restrict__ vmix, float* __restrict__ dxb, float* __restrict__ vec) {
    __shared__ ushort_t Rs[64 * 40];   // rbf tile (A-frags)
    __shared__ ushort_t Xs[64 * 136];  // x[src] bf16; later phi bf16
    __shared__ ushort_t Ts[64 * 136];  // t bf16; later filt bf16
    __shared__ int s_src[64];
    __shared__ int s_dst[64];
    __shared__ float s_dir[64 * 3];

    int tid = threadIdx.x;
    int row0 = blockIdx.x * 64;
    int w = tid >> 6;
    int lane = tid & 63;
    int c = lane & 15;
    int q = lane >> 4;

    // stage rbf tile
    {
        int r = tid >> 2;
        int c8 = tid & 3;
        *(uint4*)(Rs + r * 40 + c8 * 8) =
            *(const uint4*)(rbf16 + (size_t)(row0 + r) * 32 + c8 * 8);
    }
    if (tid < 64) {
        s_src[tid] = sperm[row0 + tid];
        s_dst[tid] = dperm[row0 + tid];
    }
    if (tid < 192) s_dir[tid] = dirn[(size_t)row0 * 3 + tid];
    // stage x[src] tile bf16: 4 threads per row
    {
        int r = tid >> 2;
        int sr = sperm[row0 + r];
        const float* xp = x + (size_t)sr * 128;
#pragma unroll
        for (int u = 0; u < 8; u++) {
            int seg = (tid & 3) * 32 + u * 4;
            float4 v = *(const float4*)(xp + seg);
            ushort_t b4[4] = {f2bf(v.x), f2bf(v.y), f2bf(v.z), f2bf(v.w)};
            *(uint2*)(Xs + r * 136 + seg) = *(uint2*)b4;
        }
    }
    __syncthreads();

    // filt = rbf @ Wrbf via MFMA (K=32)
    f32x4 facc[8];
    {
        short8 af = *(const short8*)(Rs + (w * 16 + c) * 40 + q * 8);
#pragma unroll
        for (int t8 = 0; t8 < 8; t8++) {
            short8 bfr = *(const short8*)(WrbfT + (size_t)(t8 * 16 + c) * 32 + q * 8);
            f32x4 z = {};
            facc[t8] = __builtin_amdgcn_mfma_f32_16x16x32_bf16(af, bfr, z, 0, 0, 0);
        }
    }

    // t = filt * x (D layout) -> Ts
#pragma unroll
    for (int t8 = 0; t8 < 8; t8++) {
#pragma unroll
        for (int r = 0; r < 4; r++) {
            int row = w * 16 + q * 4 + r;
            int col = t8 * 16 + c;
            float xv = bf2f(Xs[row * 136 + col]);
            Ts[row * 136 + col] = f2bf(facc[t8][r] * xv);
        }
    }
    __syncthreads();

    // phi = silu(t @ W1) via MFMA (K=128)
    f32x4 pacc[8] = {};
    const ushort_t* ap = Ts + (w * 16 + c) * 136 + q * 8;
#pragma unroll
    for (int s = 0; s < 4; s++) {
        short8 af = *(const short8*)(ap + s * 32);
#pragma unroll
        for (int t8 = 0; t8 < 8; t8++) {
            short8 bfr = *(const short8*)(W1T + (size_t)(t8 * 16 + c) * 128 + s * 32 + q * 8);
            pacc[t8] = __builtin_amdgcn_mfma_f32_16x16x32_bf16(af, bfr, pacc[t8], 0, 0, 0);
        }
    }
    __syncthreads();  // all reads of Ts(t-tile) done before overwrite

    // phi -> Xs, filt -> Ts (bf16, wave-private rows)
#pragma unroll
    for (int t8 = 0; t8 < 8; t8++) {
#pragma unroll
        for (int r = 0; r < 4; r++) {
            int row = w * 16 + q * 4 + r;
            int col = t8 * 16 + c;
            Xs[row * 136 + col] = f2bf(fast_silu(pacc[t8][r]));
            Ts[row * 136 + col] = f2bf(facc[t8][r]);
        }
    }
    __syncthreads();

    // column-parallel segmented reduction: thread = (col h, row-half)
    int h = tid & 127;
    int half = tid >> 7;
    int rbeg = half * 32;
    int rend = rbeg + 32;
    float adx = 0.f, a0 = 0.f, a1 = 0.f, a2 = 0.f;
    int cur = s_dst[rbeg];
    for (int r = rbeg; r < rend; r++) {
        int d = s_dst[r];
        if (d != cur) {
            atomicAdd(&dxb[(size_t)cur * 128 + h], adx);
            atomicAdd(&vec[((size_t)cur * 3 + 0) * 128 + h], a0);
            atomicAdd(&vec[((size_t)cur * 3 + 1) * 128 + h], a1);
            atomicAdd(&vec[((size_t)cur * 3 + 2) * 128 + h], a2);
            cur = d;
            adx = a0 = a1 = a2 = 0.f;
        }
        float f = bf2f(Ts[r * 136 + h]);
        float p = bf2f(Xs[r * 136 + h]);
        const ushort_t* vm = vmix + (size_t)s_src[r] * 384 + h;
        float d0 = s_dir[r * 3 + 0];
        float d1 = s_dir[r * 3 + 1];
        float d2 = s_dir[r * 3 + 2];
        adx += p;
        a0 += bf2f(vm[0]) * f + p * d0;
        a1 += bf2f(vm[128]) * f + p * d1;
        a2 += bf2f(vm[256]) * f + p * d2;
    }
    atomicAdd(&dxb[(size_t)cur * 128 + h], adx);
    atomicAdd(&vec[((size_t)cur * 3 + 0) * 128 + h], a0);
    atomicAdd(&vec[((size_t)cur * 3 + 1) * 128 + h], a1);
    atomicAdd(&vec[((size_t)cur * 3 + 2) * 128 + h], a2);
}

__global__ void vnorm_kernel(const float* __restrict__ v2, float* __restrict__ vnorm) {
    int i = blockIdx.x * blockDim.x + threadIdx.x;
    if (i >= N_NODES * HIDDEN) return;
    int n = i >> 7;
    int h = i & 127;
    float a = v2[(size_t)(n * 3 + 0) * 128 + h];
    float b = v2[(size_t)(n * 3 + 1) * 128 + h];
    float c = v2[(size_t)(n * 3 + 2) * 128 + h];
    vnorm[i] = sqrtf(a * a + b * b + c * c + EPS);
}

__global__ void out_pool_kernel(const float* __restrict__ a, const float* __restrict__ W_b,
                                const float* __restrict__ b_b, const int* __restrict__ batch,
                                float* __restrict__ pooled) {
    __shared__ float sa[HIDDEN];
    int n = blockIdx.x;
    int h = threadIdx.x;
    sa[h] = a[(size_t)n * 128 + h];
    __syncthreads();
    if (h < LATENT + 1) {
        float o = b_b[h];
        for (int j = 0; j < HIDDEN; j++) o += sa[j] * W_b[j * (LATENT + 1) + h];
        atomicAdd(&pooled[batch[n] * (LATENT + 1) + h], o);
    }
}

__global__ void finalize_kernel(const float* __restrict__ pooled, float* __restrict__ out) {
    int i = blockIdx.x * blockDim.x + threadIdx.x;
    if (i >= N_GRAPHS * (LATENT + 1)) return;
    int g = i / (LATENT + 1);
    int k = i % (LATENT + 1);
    float v = pooled[i];
    if (k < LATENT) {
        out[g * LATENT + k] = v;
    } else {
        v = fminf(fmaxf(v, -10.0f), 2.0f);
        out[N_GRAPHS * LATENT + g] = v;
    }
}

extern "C" void kernel_launch(void* const* d_in, const int* in_sizes, int n_in,
                              void* d_out, int out_size, void* d_ws, size_t ws_size,
                              hipStream_t stream) {
    const int* z = (const int*)d_in[0];
    const float* pos = (const float*)d_in[1];
    const int* batch = (const int*)d_in[2];
    const int* ei = (const int*)d_in[3];
    const float* embed = (const float*)d_in[4];
    const float* W_rbf = (const float*)d_in[5];
    const float* W1 = (const float*)d_in[6];
    const float* Wo = (const float*)d_in[7];
    const float* Wv = (const float*)d_in[8];
    const float* Wvec2 = (const float*)d_in[10];
    const float* W_a = (const float*)d_in[11];
    const float* b_a = (const float*)d_in[12];
    const float* W_b = (const float*)d_in[13];
    const float* b_b = (const float*)d_in[14];
    float* out = (float*)d_out;

    const int* srcs = ei;
    const int* dsts = ei + N_EDGES;

    float* ws = (float*)d_ws;
    float* dirn = ws;                              // E*3 (permuted)
    float* x = dirn + (size_t)N_EDGES * 3;         // N*128
    float* vec = x + (size_t)N_NODES * 128;        // N*384
    float* vbuf = vec + (size_t)N_NODES * 384;     // N*384 (v2 fp32)
    float* dxb = vbuf + (size_t)N_NODES * 384;     // N*128 (later vnorm)
    float* tmpa = dxb + (size_t)N_NODES * 128;     // N*128
    float* abuf = tmpa + (size_t)N_NODES * 128;    // N*128
    float* pooled = abuf + (size_t)N_NODES * 128;  // 128*65 (+pad)
    ushort_t* rbf16 = (ushort_t*)(pooled + N_GRAPHS * (LATENT + 1) + 16);
    ushort_t* vmix16 = rbf16 + (size_t)N_EDGES * 32;   // N*384
    ushort_t* W1T = vmix16 + (size_t)N_NODES * 384;    // 2*128*128
    ushort_t* WrbfT = W1T + 2 * 128 * 128;             // 2*128*32
    int* ibase = (int*)(WrbfT + 2 * 128 * 32);
    int* deg = ibase;               // N
    int* cursor = deg + N_NODES;    // N
    int* eperm = cursor + N_NODES;  // E
    int* sperm = eperm + N_EDGES;   // E
    int* dperm = sperm + N_EDGES;   // E

    // CSR permutation + geometry (permuted order) + weight prep
    zero_i_kernel<<<(N_NODES + 255) / 256, 256, 0, stream>>>(deg, N_NODES);
    hist_kernel<<<(N_EDGES + 255) / 256, 256, 0, stream>>>(dsts, deg);
    prefix_kernel<<<1, 1024, 0, stream>>>(deg, cursor);
    scatter_kernel<<<(N_EDGES + 255) / 256, 256, 0, stream>>>(srcs, dsts, cursor, eperm, sperm,
                                                              dperm);
    geom_kernel<<<(N_EDGES + 255) / 256, 256, 0, stream>>>(pos, ei, eperm, rbf16, dirn);
    wprep_kernel<<<(2 * 128 * 128 + 255) / 256, 256, 0, stream>>>(W1, W_rbf, W1T, WrbfT);

    init_x_kernel<<<(N_NODES * HIDDEN + 255) / 256, 256, 0, stream>>>(z, embed, x);
    zero_f_kernel<<<(N_NODES * 384 + 255) / 256, 256, 0, stream>>>(vec, N_NODES * 384);

    for (int l = 0; l < 2; l++) {
        gemm_nn<128, 8><<<(N_NODES * 3 + 63) / 64, 256, 0, stream>>>(
            vec, Wv + (size_t)l * 128 * 128, nullptr, nullptr, (float*)vmix16, N_NODES * 3);
        zero_f_kernel<<<(N_NODES * 128 + 255) / 256, 256, 0, stream>>>(dxb, N_NODES * 128);
        edge_fused<<<N_EDGES / 64, 256, 0, stream>>>(rbf16, WrbfT + (size_t)l * 128 * 32, x,
                                                     sperm, dperm, W1T + (size_t)l * 128 * 128,
                                                     dirn, vmix16, dxb, vec);
        gemm_nn<128, 2><<<(N_NODES + 63) / 64, 256, 0, stream>>>(
            dxb, Wo + (size_t)l * 128 * 128, nullptr, x, x, N_NODES);
    }

    gemm_nn<128, 0><<<(N_NODES * 3 + 63) / 64, 256, 0, stream>>>(vec, Wvec2, nullptr, nullptr,
                                                                 vbuf, N_NODES * 3);
    vnorm_kernel<<<(N_NODES * HIDDEN + 255) / 256, 256, 0, stream>>>(vbuf, dxb);
    gemm_nn<128, 1><<<(N_NODES + 63) / 64, 256, 0, stream>>>(x, W_a, b_a, nullptr, tmpa, N_NODES);
    gemm_nn<128, 6><<<(N_NODES + 63) / 64, 256, 0, stream>>>(dxb, W_a + 128 * 128, nullptr, tmpa,
                                                             abuf, N_NODES);

    zero_f_kernel<<<(N_GRAPHS * (LATENT + 1) + 255) / 256, 256, 0, stream>>>(
        pooled, N_GRAPHS * (LATENT + 1));
    out_pool_kernel<<<N_NODES, 128, 0, stream>>>(abuf, W_b, b_b, batch, pooled);
    finalize_kernel<<<(N_GRAPHS * (LATENT + 1) + 255) / 256, 256, 0, stream>>>(pooled, out);
}

// Round 7
// 403.149 us; speedup vs baseline: 2.5480x; 1.3714x over previous
//
#include <hip/hip_runtime.h>
#include <math.h>

#define N_NODES 10000
#define N_EDGES 160000
#define HIDDEN 128
#define NUM_RBF 32
#define LATENT 64
#define N_GRAPHS 128
#define CUTOFF 5.0f
#define EPS 1e-8f

typedef __attribute__((ext_vector_type(8))) short short8;
typedef __attribute__((ext_vector_type(4))) float f32x4;
typedef unsigned short ushort_t;

__device__ __forceinline__ float fast_silu(float v) {
    return v * __builtin_amdgcn_rcpf(1.0f + __expf(-v));
}

__device__ __forceinline__ ushort_t f2bf(float f) {
    union { float f; unsigned u; } v;
    v.f = f;
    unsigned r = v.u + 0x7FFFu + ((v.u >> 16) & 1u);  // RNE
    return (ushort_t)(r >> 16);
}
__device__ __forceinline__ float bf2f(ushort_t u) {
    union { unsigned u; float f; } v;
    v.u = ((unsigned)u) << 16;
    return v.f;
}

// one kernel: vec=0, dxb=0, pooled=0, deg=0, x=embed[z]
__global__ void init_kernel(const int* __restrict__ z, const float* __restrict__ embed,
                            float* __restrict__ x, float* __restrict__ vec,
                            float* __restrict__ dxb, float* __restrict__ pooled,
                            int* __restrict__ deg) {
    int i = blockIdx.x * blockDim.x + threadIdx.x;
    if (i < N_NODES * 384) vec[i] = 0.0f;
    if (i < N_NODES * 128) {
        x[i] = embed[z[i >> 7] * 128 + (i & 127)];
        dxb[i] = 0.0f;
    }
    if (i < N_NODES) deg[i] = 0;
    if (i < N_GRAPHS * (LATENT + 1)) pooled[i] = 0.0f;
}

__global__ void hist_kernel(const int* __restrict__ dst, int* __restrict__ deg) {
    int e = blockIdx.x * blockDim.x + threadIdx.x;
    if (e < N_EDGES) atomicAdd(&deg[dst[e]], 1);
}

__global__ void prefix_kernel(const int* __restrict__ deg, int* __restrict__ cursor) {
    __shared__ int part[1024];
    const int ITEMS = 10;
    int t = threadIdx.x;
    int base = t * ITEMS;
    int local[ITEMS];
    int s = 0;
#pragma unroll
    for (int j = 0; j < ITEMS; j++) {
        int idx = base + j;
        int v = (idx < N_NODES) ? deg[idx] : 0;
        local[j] = s;
        s += v;
    }
    part[t] = s;
    __syncthreads();
    for (int off = 1; off < 1024; off <<= 1) {
        int v = (t >= off) ? part[t - off] : 0;
        __syncthreads();
        part[t] += v;
        __syncthreads();
    }
    int base_sum = (t > 0) ? part[t - 1] : 0;
#pragma unroll
    for (int j = 0; j < ITEMS; j++) {
        int idx = base + j;
        if (idx < N_NODES) cursor[idx] = base_sum + local[j];
    }
}

__global__ void scatter_kernel(const int* __restrict__ src, const int* __restrict__ dst,
                               int* __restrict__ cursor, int* __restrict__ eperm,
                               int* __restrict__ sperm, int* __restrict__ dperm) {
    int e = blockIdx.x * blockDim.x + threadIdx.x;
    if (e < N_EDGES) {
        int d = dst[e];
        int p = atomicAdd(&cursor[d], 1);
        eperm[p] = e;
        sperm[p] = src[e];
        dperm[p] = d;
    }
}

// geometry in PERMUTED (dst-sorted) order
__global__ void geom_kernel(const float* __restrict__ pos, const int* __restrict__ ei,
                            const int* __restrict__ eperm, ushort_t* __restrict__ rbf16,
                            float* __restrict__ dirn) {
    int i = blockIdx.x * blockDim.x + threadIdx.x;
    if (i >= N_EDGES) return;
    int e = eperm[i];
    int s = ei[e];
    int t = ei[N_EDGES + e];
    float dx = pos[t * 3 + 0] - pos[s * 3 + 0];
    float dy = pos[t * 3 + 1] - pos[s * 3 + 1];
    float dz = pos[t * 3 + 2] - pos[s * 3 + 2];
    float r = sqrtf(dx * dx + dy * dy + dz * dz + EPS);
    float inv = 1.0f / r;
    dirn[i * 3 + 0] = dx * inv;
    dirn[i * 3 + 1] = dy * inv;
    dirn[i * 3 + 2] = dz * inv;

    float e5 = __expf(-CUTOFF);
    float span = 1.0f - e5;
    float b = (2.0f / NUM_RBF) * span;
    float beta = 1.0f / (b * b);
    float cut = (r < CUTOFF) ? 0.5f * (__cosf((float)M_PI * r / CUTOFF) + 1.0f) : 0.0f;
    float er = __expf(-r);
#pragma unroll
    for (int k = 0; k < NUM_RBF; k++) {
        float mean = e5 + span * ((float)k / (NUM_RBF - 1));
        float d = er - mean;
        rbf16[(size_t)i * 32 + k] = f2bf(cut * __expf(-beta * d * d));
    }
}

// all weight transposes to bf16: WT[n][k] = bf16(W[k][n])
__global__ void wprep_kernel(const float* __restrict__ W1, const float* __restrict__ Wrbf,
                             const float* __restrict__ Wv, const float* __restrict__ Wo,
                             const float* __restrict__ Wvec2, const float* __restrict__ W_a,
                             ushort_t* __restrict__ W1T, ushort_t* __restrict__ WrbfT,
                             ushort_t* __restrict__ WvT, ushort_t* __restrict__ WoT,
                             ushort_t* __restrict__ Wvec2T, ushort_t* __restrict__ W_aT) {
    int i = blockIdx.x * blockDim.x + threadIdx.x;
    if (i < 2 * 128 * 128) {
        int l = i >> 14;
        int n = (i & 16383) >> 7;
        int k = i & 127;
        W1T[i] = f2bf(W1[l * 16384 + k * 128 + n]);
        WvT[i] = f2bf(Wv[l * 16384 + k * 128 + n]);
        WoT[i] = f2bf(Wo[l * 16384 + k * 128 + n]);
    }
    if (i < 2 * 128 * 32) {
        int l = i >> 12;
        int n = (i & 4095) >> 5;
        int k = i & 31;
        WrbfT[i] = f2bf(Wrbf[l * 4096 + k * 128 + n]);
    }
    if (i < 128 * 128) {
        int n = i >> 7;
        int k = i & 127;
        Wvec2T[i] = f2bf(Wvec2[k * 128 + n]);
    }
    if (i < 128 * 256) {
        int n = i >> 8;
        int k = i & 255;
        W_aT[i] = f2bf(W_a[k * 128 + n]);
    }
}

// ---------- MFMA node GEMM: C = epi(bf16(A | A2)[MxK] @ WT^T [Kx128]) ----------
// EPI bits: 1=bias, 2=add Cin, 4=silu, 8=bf16 out (K=128 only), 16=zero A after read
template <int K, int EPI>
__global__ __launch_bounds__(256, 4) void gemm_mfma(float* __restrict__ A,
                                                    const float* __restrict__ A2,
                                                    const ushort_t* __restrict__ WT,
                                                    const float* __restrict__ bias,
                                                    const float* __restrict__ Cin,
                                                    float* __restrict__ C, int M) {
    constexpr int STR = K + 8;
    __shared__ ushort_t As[64 * STR];
    int tid = threadIdx.x;
    int row0 = blockIdx.x * 64;
    int w = tid >> 6;
    int lane = tid & 63;
    int c = lane & 15;
    int q = lane >> 4;

    // stage A (and A2 for K=256) -> bf16 LDS; 4 threads per row
    {
        int r = tid >> 2;
        int row = row0 + r;
        if (row < M) {
            int segbase = (tid & 3) * (K / 4);
#pragma unroll
            for (int u = 0; u < K / 16; u++) {
                int k0 = segbase + u * 4;
                const float* src = (K == 256 && k0 >= 128)
                                       ? (A2 + (size_t)row * 128 + (k0 - 128))
                                       : (A + (size_t)row * 128 + k0);
                float4 v = *(const float4*)src;
                ushort_t b4[4] = {f2bf(v.x), f2bf(v.y), f2bf(v.z), f2bf(v.w)};
                *(uint2*)(As + r * STR + k0) = *(uint2*)b4;
            }
            if (EPI & 16) {
                float4 z4 = make_float4(0.f, 0.f, 0.f, 0.f);
#pragma unroll
                for (int u = 0; u < 8; u++)
                    *(float4*)(A + (size_t)row * 128 + (tid & 3) * 32 + u * 4) = z4;
            }
        }
    }
    __syncthreads();

    f32x4 acc[8] = {};
#pragma unroll
    for (int s = 0; s < K / 32; s++) {
        short8 af = *(const short8*)(As + (w * 16 + c) * STR + s * 32 + q * 8);
#pragma unroll
        for (int t8 = 0; t8 < 8; t8++) {
            short8 bf = *(const short8*)(WT + (size_t)(t8 * 16 + c) * K + s * 32 + q * 8);
            acc[t8] = __builtin_amdgcn_mfma_f32_16x16x32_bf16(af, bf, acc[t8], 0, 0, 0);
        }
    }

    if (EPI & 8) {
        // bf16 out via LDS round-trip (K=128 path; STR=136 tile reused)
        __syncthreads();
#pragma unroll
        for (int t8 = 0; t8 < 8; t8++) {
#pragma unroll
            for (int r4 = 0; r4 < 4; r4++) {
                int lrow = w * 16 + q * 4 + r4;
                As[lrow * 136 + t8 * 16 + c] = f2bf(acc[t8][r4]);
            }
        }
        __syncthreads();
        for (int idx = tid; idx < 64 * 16; idx += 256) {
            int r = idx >> 4;
            int c8 = idx & 15;
            if (row0 + r < M)
                *(uint4*)((ushort_t*)C + (size_t)(row0 + r) * 128 + c8 * 8) =
                    *(uint4*)(As + r * 136 + c8 * 8);
        }
    } else {
#pragma unroll
        for (int t8 = 0; t8 < 8; t8++) {
#pragma unroll
            for (int r4 = 0; r4 < 4; r4++) {
                int row = row0 + w * 16 + q * 4 + r4;
                if (row < M) {
                    int col = t8 * 16 + c;
                    float o = acc[t8][r4];
                    if (EPI & 1) o += bias[col];
                    if (EPI & 2) o += Cin[(size_t)row * 128 + col];
                    if (EPI & 4) o = fast_silu(o);
                    C[(size_t)row * 128 + col] = o;
                }
            }
        }
    }
}

// ------- fused edge kernel: MFMA filt -> t -> MFMA phi -> column-parallel segmented scatter -------
template <bool HASV>
__global__ __launch_bounds__(256, 4) void edge_fused(
    const ushort_t* __restrict__ rbf16, const ushort_t* __restrict__ WrbfT,
    const float* __restrict__ x, const int* __restrict__ sperm, const int* __restrict__ dperm,
    const ushort_t* __restrict__ W1T, const float* __restrict__ dirn,
    const ushort_t* __restrict__ vmix, float* __restrict__ dxb, float* __restrict__ vec) {
    __shared__ ushort_t Xs[64 * 136];  // x[src] bf16; later phi bf16
    __shared__ ushort_t Ts[64 * 136];  // t bf16; later filt bf16
    __shared__ int s_src[64];
    __shared__ int s_dst[64];
    __shared__ float s_dir[64 * 3];

    int tid = threadIdx.x;
    int row0 = blockIdx.x * 64;
    int w = tid >> 6;
    int lane = tid & 63;
    int c = lane & 15;
    int q = lane >> 4;

    if (tid < 64) {
        s_src[tid] = sperm[row0 + tid];
        s_dst[tid] = dperm[row0 + tid];
    }
    if (tid < 192) s_dir[tid] = dirn[(size_t)row0 * 3 + tid];
    // stage x[src] tile bf16: 4 threads per row (rows wave-private to wave tid>>6)
    {
        int r = tid >> 2;
        int sr = sperm[row0 + r];
        const float* xp = x + (size_t)sr * 128;
#pragma unroll
        for (int u = 0; u < 8; u++) {
            int seg = (tid & 3) * 32 + u * 4;
            float4 v = *(const float4*)(xp + seg);
            ushort_t b4[4] = {f2bf(v.x), f2bf(v.y), f2bf(v.z), f2bf(v.w)};
            *(uint2*)(Xs + r * 136 + seg) = *(uint2*)b4;
        }
    }
    __syncthreads();

    // filt = rbf @ Wrbf via MFMA (K=32); A-frags straight from global (coalesced)
    f32x4 facc[8];
    {
        short8 af = *(const short8*)(rbf16 + (size_t)(row0 + w * 16 + c) * 32 + q * 8);
#pragma unroll
        for (int t8 = 0; t8 < 8; t8++) {
            short8 bfr = *(const short8*)(WrbfT + (size_t)(t8 * 16 + c) * 32 + q * 8);
            f32x4 z = {};
            facc[t8] = __builtin_amdgcn_mfma_f32_16x16x32_bf16(af, bfr, z, 0, 0, 0);
        }
    }

    // t = filt * x (D layout, wave-private rows) -> Ts
#pragma unroll
    for (int t8 = 0; t8 < 8; t8++) {
#pragma unroll
        for (int r = 0; r < 4; r++) {
            int row = w * 16 + q * 4 + r;
            int col = t8 * 16 + c;
            float xv = bf2f(Xs[row * 136 + col]);
            Ts[row * 136 + col] = f2bf(facc[t8][r] * xv);
        }
    }

    // phi = silu(t @ W1) via MFMA (K=128), wave-private rows
    f32x4 pacc[8] = {};
    const ushort_t* ap = Ts + (w * 16 + c) * 136 + q * 8;
#pragma unroll
    for (int s = 0; s < 4; s++) {
        short8 af = *(const short8*)(ap + s * 32);
#pragma unroll
        for (int t8 = 0; t8 < 8; t8++) {
            short8 bfr = *(const short8*)(W1T + (size_t)(t8 * 16 + c) * 128 + s * 32 + q * 8);
            pacc[t8] = __builtin_amdgcn_mfma_f32_16x16x32_bf16(af, bfr, pacc[t8], 0, 0, 0);
        }
    }

    // phi -> Xs, filt -> Ts (bf16, wave-private rows)
#pragma unroll
    for (int t8 = 0; t8 < 8; t8++) {
#pragma unroll
        for (int r = 0; r < 4; r++) {
            int row = w * 16 + q * 4 + r;
            int col = t8 * 16 + c;
            Xs[row * 136 + col] = f2bf(fast_silu(pacc[t8][r]));
            Ts[row * 136 + col] = f2bf(facc[t8][r]);
        }
    }
    __syncthreads();

    // column-parallel segmented reduction; vmix loads batched in groups of 8
    int h = tid & 127;
    int half = tid >> 7;
    int rbeg = half * 32;
    float adx = 0.f, a0 = 0.f, a1 = 0.f, a2 = 0.f;
    int cur = s_dst[rbeg];
#pragma unroll
    for (int g = 0; g < 4; g++) {
        float v0[8], v1[8], v2[8];
        if (HASV) {
#pragma unroll
            for (int j = 0; j < 8; j++) {
                const ushort_t* vm = vmix + (size_t)s_src[rbeg + g * 8 + j] * 384 + h;
                v0[j] = bf2f(vm[0]);
                v1[j] = bf2f(vm[128]);
                v2[j] = bf2f(vm[256]);
            }
        }
#pragma unroll
        for (int j = 0; j < 8; j++) {
            int r = rbeg + g * 8 + j;
            int d = s_dst[r];
            if (d != cur) {
                atomicAdd(&dxb[(size_t)cur * 128 + h], adx);
                atomicAdd(&vec[((size_t)cur * 3 + 0) * 128 + h], a0);
                atomicAdd(&vec[((size_t)cur * 3 + 1) * 128 + h], a1);
                atomicAdd(&vec[((size_t)cur * 3 + 2) * 128 + h], a2);
                cur = d;
                adx = a0 = a1 = a2 = 0.f;
            }
            float f = bf2f(Ts[r * 136 + h]);
            float p = bf2f(Xs[r * 136 + h]);
            float d0 = s_dir[r * 3 + 0];
            float d1 = s_dir[r * 3 + 1];
            float d2 = s_dir[r * 3 + 2];
            adx += p;
            if (HASV) {
                a0 += v0[j] * f + p * d0;
                a1 += v1[j] * f + p * d1;
                a2 += v2[j] * f + p * d2;
            } else {
                a0 += p * d0;
                a1 += p * d1;
                a2 += p * d2;
            }
        }
    }
    atomicAdd(&dxb[(size_t)cur * 128 + h], adx);
    atomicAdd(&vec[((size_t)cur * 3 + 0) * 128 + h], a0);
    atomicAdd(&vec[((size_t)cur * 3 + 1) * 128 + h], a1);
    atomicAdd(&vec[((size_t)cur * 3 + 2) * 128 + h], a2);
}

__global__ void vnorm_kernel(const float* __restrict__ v2, float* __restrict__ vnorm) {
    int i = blockIdx.x * blockDim.x + threadIdx.x;
    if (i >= N_NODES * HIDDEN) return;
    int n = i >> 7;
    int h = i & 127;
    float a = v2[(size_t)(n * 3 + 0) * 128 + h];
    float b = v2[(size_t)(n * 3 + 1) * 128 + h];
    float c = v2[(size_t)(n * 3 + 2) * 128 + h];
    vnorm[i] = sqrtf(a * a + b * b + c * c + EPS);
}

__global__ void out_pool_kernel(const float* __restrict__ a, const float* __restrict__ W_b,
                                const float* __restrict__ b_b, const int* __restrict__ batch,
                                float* __restrict__ pooled) {
    __shared__ float sa[HIDDEN];
    int n = blockIdx.x;
    int h = threadIdx.x;
    sa[h] = a[(size_t)n * 128 + h];
    __syncthreads();
    if (h < LATENT + 1) {
        float o = b_b[h];
        for (int j = 0; j < HIDDEN; j++) o += sa[j] * W_b[j * (LATENT + 1) + h];
        atomicAdd(&pooled[batch[n] * (LATENT + 1) + h], o);
    }
}

__global__ void finalize_kernel(const float* __restrict__ pooled, float* __restrict__ out) {
    int i = blockIdx.x * blockDim.x + threadIdx.x;
    if (i >= N_GRAPHS * (LATENT + 1)) return;
    int g = i / (LATENT + 1);
    int k = i % (LATENT + 1);
    float v = pooled[i];
    if (k < LATENT) {
        out[g * LATENT + k] = v;
    } else {
        v = fminf(fmaxf(v, -10.0f), 2.0f);
        out[N_GRAPHS * LATENT + g] = v;
    }
}

extern "C" void kernel_launch(void* const* d_in, const int* in_sizes, int n_in,
                              void* d_out, int out_size, void* d_ws, size_t ws_size,
                              hipStream_t stream) {
    const int* z = (const int*)d_in[0];
    const float* pos = (const float*)d_in[1];
    const int* batch = (const int*)d_in[2];
    const int* ei = (const int*)d_in[3];
    const float* embed = (const float*)d_in[4];
    const float* W_rbf = (const float*)d_in[5];
    const float* W1 = (const float*)d_in[6];
    const float* Wo = (const float*)d_in[7];
    const float* Wv = (const float*)d_in[8];
    const float* Wvec2 = (const float*)d_in[10];
    const float* W_a = (const float*)d_in[11];
    const float* b_a = (const float*)d_in[12];
    const float* W_b = (const float*)d_in[13];
    const float* b_b = (const float*)d_in[14];
    float* out = (float*)d_out;

    const int* srcs = ei;
    const int* dsts = ei + N_EDGES;

    float* ws = (float*)d_ws;
    float* dirn = ws;                              // E*3 (permuted)
    float* x = dirn + (size_t)N_EDGES * 3;         // N*128
    float* vec = x + (size_t)N_NODES * 128;        // N*384
    float* vbuf = vec + (size_t)N_NODES * 384;     // N*384 (v2 fp32)
    float* dxb = vbuf + (size_t)N_NODES * 384;     // N*128 (later vnorm)
    float* abuf = dxb + (size_t)N_NODES * 128;     // N*128
    float* pooled = abuf + (size_t)N_NODES * 128;  // 128*65 (+pad)
    ushort_t* rbf16 = (ushort_t*)(pooled + N_GRAPHS * (LATENT + 1) + 16);
    ushort_t* vmix16 = rbf16 + (size_t)N_EDGES * 32;  // N*384
    ushort_t* W1T = vmix16 + (size_t)N_NODES * 384;   // 2*16384
    ushort_t* WrbfT = W1T + 2 * 16384;                // 2*4096
    ushort_t* WvT = WrbfT + 2 * 4096;                 // 2*16384
    ushort_t* WoT = WvT + 2 * 16384;                  // 2*16384
    ushort_t* Wvec2T = WoT + 2 * 16384;               // 16384
    ushort_t* W_aT = Wvec2T + 16384;                  // 32768
    int* ibase = (int*)(W_aT + 32768);
    int* deg = ibase;               // N
    int* cursor = deg + N_NODES;    // N
    int* eperm = cursor + N_NODES;  // E
    int* sperm = eperm + N_EDGES;   // E
    int* dperm = sperm + N_EDGES;   // E

    init_kernel<<<(N_NODES * 384 + 255) / 256, 256, 0, stream>>>(z, embed, x, vec, dxb, pooled,
                                                                 deg);
    hist_kernel<<<(N_EDGES + 255) / 256, 256, 0, stream>>>(dsts, deg);
    prefix_kernel<<<1, 1024, 0, stream>>>(deg, cursor);
    scatter_kernel<<<(N_EDGES + 255) / 256, 256, 0, stream>>>(srcs, dsts, cursor, eperm, sperm,
                                                              dperm);
    geom_kernel<<<(N_EDGES + 255) / 256, 256, 0, stream>>>(pos, ei, eperm, rbf16, dirn);
    wprep_kernel<<<(128 * 256 + 255) / 256, 256, 0, stream>>>(W1, W_rbf, Wv, Wo, Wvec2, W_a, W1T,
                                                              WrbfT, WvT, WoT, Wvec2T, W_aT);

    // ---- layer 0 (vec==0 -> vmix==0: skip vmix GEMM, skip vmix reads) ----
    edge_fused<false><<<N_EDGES / 64, 256, 0, stream>>>(rbf16, WrbfT, x, sperm, dperm, W1T, dirn,
                                                        nullptr, dxb, vec);
    // x += dxb @ Wo[0]; zero dxb for next layer
    gemm_mfma<128, 2 | 16><<<(N_NODES + 63) / 64, 256, 0, stream>>>(dxb, nullptr, WoT, nullptr, x,
                                                                    x, N_NODES);
    // ---- layer 1 ----
    gemm_mfma<128, 8><<<(N_NODES * 3 + 63) / 64, 256, 0, stream>>>(vec, nullptr, WvT + 16384,
                                                                   nullptr, nullptr,
                                                                   (float*)vmix16, N_NODES * 3);
    edge_fused<true><<<N_EDGES / 64, 256, 0, stream>>>(rbf16, WrbfT + 4096, x, sperm, dperm,
                                                       W1T + 16384, dirn, vmix16, dxb, vec);
    gemm_mfma<128, 2><<<(N_NODES + 63) / 64, 256, 0, stream>>>(dxb, nullptr, WoT + 16384, nullptr,
                                                               x, x, N_NODES);

    // ---- readout ----
    gemm_mfma<128, 0><<<(N_NODES * 3 + 63) / 64, 256, 0, stream>>>(vec, nullptr, Wvec2T, nullptr,
                                                                   nullptr, vbuf, N_NODES * 3);
    vnorm_kernel<<<(N_NODES * HIDDEN + 255) / 256, 256, 0, stream>>>(vbuf, dxb);
    // a = silu([x, vnorm] @ W_a + b_a)  (K=256)
    gemm_mfma<256, 1 | 4><<<(N_NODES + 63) / 64, 256, 0, stream>>>(x, dxb, W_aT, b_a, nullptr,
                                                                   abuf, N_NODES);
    out_pool_kernel<<<N_NODES, 128, 0, stream>>>(abuf, W_b, b_b, batch, pooled);
    finalize_kernel<<<(N_GRAPHS * (LATENT + 1) + 255) / 256, 256, 0, stream>>>(pooled, out);
}